// Round 1
// baseline (5445.885 us; speedup 1.0000x reference)
//
#include <hip/hip_runtime.h>
#include <math.h>

#define SLOPE 0.01f

__device__ __forceinline__ float lrelu(float x) {
    return x > 0.f ? x : SLOPE * x;
}

// ---------------------------------------------------------------------------
// Conv 4->4, SAME padding, square kernel K, fused bias + LeakyReLU.
// One thread per (n, h, w); computes all 4 output channels.
// in/out: [N,4,84,84] f32
// ---------------------------------------------------------------------------
template<int K>
__global__ void conv_lrelu_kernel(const float* __restrict__ in,
                                  const float* __restrict__ w,
                                  const float* __restrict__ b,
                                  float* __restrict__ out, int total) {
    constexpr int PAD = K / 2;
    __shared__ float ws[16 * K * K];
    __shared__ float bs[4];
    int tid = threadIdx.x;
    for (int i = tid; i < 16 * K * K; i += blockDim.x) ws[i] = w[i];
    if (tid < 4) bs[tid] = b[tid];
    __syncthreads();

    int idx = blockIdx.x * blockDim.x + tid;
    if (idx >= total) return;
    int ww_ = idx % 84;
    int t   = idx / 84;
    int hh  = t % 84;
    int n   = t / 84;

    float acc0 = bs[0], acc1 = bs[1], acc2 = bs[2], acc3 = bs[3];
    const float* inN = in + (size_t)n * (4 * 84 * 84);
    #pragma unroll
    for (int ci = 0; ci < 4; ++ci) {
        #pragma unroll
        for (int kh = 0; kh < K; ++kh) {
            int ih = hh + kh - PAD;
            if ((unsigned)ih >= 84u) continue;
            #pragma unroll
            for (int kw = 0; kw < K; ++kw) {
                int iw = ww_ + kw - PAD;
                if ((unsigned)iw >= 84u) continue;
                float v = inN[(ci * 84 + ih) * 84 + iw];
                acc0 += v * ws[((0 * 4 + ci) * K + kh) * K + kw];
                acc1 += v * ws[((1 * 4 + ci) * K + kh) * K + kw];
                acc2 += v * ws[((2 * 4 + ci) * K + kh) * K + kw];
                acc3 += v * ws[((3 * 4 + ci) * K + kh) * K + kw];
            }
        }
    }
    float* outN = out + (size_t)n * (4 * 84 * 84);
    outN[(0 * 84 + hh) * 84 + ww_] = lrelu(acc0);
    outN[(1 * 84 + hh) * 84 + ww_] = lrelu(acc1);
    outN[(2 * 84 + hh) * 84 + ww_] = lrelu(acc2);
    outN[(3 * 84 + hh) * 84 + ww_] = lrelu(acc3);
}

// ---------------------------------------------------------------------------
// GEMM (NT): C[M,N] = A[M,K] * B[N,K]^T + bias (+bias2), optional LeakyReLU.
// BM=64, BN=32, BK=16, 256 threads, 4x2 micro-tile.
// Requires: M%64==0, N%32==0, K%16==0 (true for every call here).
// ---------------------------------------------------------------------------
template<bool DO_LRELU, bool BIAS2>
__global__ void gemm_nt_kernel(const float* __restrict__ A,
                               const float* __restrict__ B,
                               const float* __restrict__ bias,
                               const float* __restrict__ bias2,
                               float* __restrict__ C,
                               int M, int N, int K) {
    __shared__ float As[16][65];
    __shared__ float Bs[16][33];
    int tid = threadIdx.x;
    int rowBase = blockIdx.y * 64;
    int colBase = blockIdx.x * 32;

    int ar = tid >> 2, ak = (tid & 3) << 2;   // A: 64 rows x 16 k, float4/thread
    int br = tid >> 3, bk = (tid & 7) << 1;   // B: 32 rows x 16 k, float2/thread
    const float* Aptr = A + (size_t)(rowBase + ar) * K + ak;
    const float* Bptr = B + (size_t)(colBase + br) * K + bk;

    int ty = tid >> 4, tx = tid & 15;
    float acc[4][2] = {};

    for (int k0 = 0; k0 < K; k0 += 16) {
        float4 av = *(const float4*)(Aptr + k0);
        float2 bv = *(const float2*)(Bptr + k0);
        __syncthreads();
        As[ak + 0][ar] = av.x; As[ak + 1][ar] = av.y;
        As[ak + 2][ar] = av.z; As[ak + 3][ar] = av.w;
        Bs[bk + 0][br] = bv.x; Bs[bk + 1][br] = bv.y;
        __syncthreads();
        #pragma unroll
        for (int kk = 0; kk < 16; ++kk) {
            float a0 = As[kk][ty * 4 + 0];
            float a1 = As[kk][ty * 4 + 1];
            float a2 = As[kk][ty * 4 + 2];
            float a3 = As[kk][ty * 4 + 3];
            float b0 = Bs[kk][tx * 2 + 0];
            float b1 = Bs[kk][tx * 2 + 1];
            acc[0][0] += a0 * b0; acc[0][1] += a0 * b1;
            acc[1][0] += a1 * b0; acc[1][1] += a1 * b1;
            acc[2][0] += a2 * b0; acc[2][1] += a2 * b1;
            acc[3][0] += a3 * b0; acc[3][1] += a3 * b1;
        }
    }

    #pragma unroll
    for (int i = 0; i < 4; ++i) {
        int row = rowBase + ty * 4 + i;
        #pragma unroll
        for (int j = 0; j < 2; ++j) {
            int col = colBase + tx * 2 + j;
            float v = acc[i][j] + bias[col];
            if (BIAS2) v += bias2[col];
            if (DO_LRELU) v = lrelu(v);
            C[(size_t)row * N + col] = v;
        }
    }
}

// ---------------------------------------------------------------------------
// Copy h0 -> hA, c0 -> c_buf (each 32*512 = 16384 f32)
// ---------------------------------------------------------------------------
__global__ void init_state_kernel(const float* __restrict__ h0,
                                  const float* __restrict__ c0,
                                  float* __restrict__ hA,
                                  float* __restrict__ cb) {
    int i = blockIdx.x * blockDim.x + threadIdx.x;
    if (i < 16384) { hA[i] = h0[i]; cb[i] = c0[i]; }
}

// ---------------------------------------------------------------------------
// One LSTM time step. Grid: 64 blocks; block (32,8): x = batch b, y = local j.
// Each thread owns (b, j): computes all 4 gate dots over masked h_prev staged
// in LDS (transposed [k][b], padded), then the pointwise cell update.
// gx already holds x@w_ih.T + b_ih + b_hh.
// ---------------------------------------------------------------------------
__global__ void lstm_step_kernel(const float* __restrict__ gx,   // [2048,2048]
                                 const float* __restrict__ done, // [2048]
                                 const float* __restrict__ whh,  // [2048,512]
                                 const float* __restrict__ h_in, // [32,512]
                                 float* __restrict__ h_out,      // [32,512]
                                 float* __restrict__ c_buf,      // [32,512]
                                 float* __restrict__ feat,       // [2048,512]
                                 float* __restrict__ hN,         // null unless t==63
                                 float* __restrict__ cN,
                                 int t) {
    __shared__ float Hs[512 * 33];   // Hs[k][b], padded stride 33
    __shared__ float mds[32];
    int tid = threadIdx.y * 32 + threadIdx.x;
    if (tid < 32) mds[tid] = 1.0f - done[t * 32 + tid];
    __syncthreads();

    // stage masked h_prev, transposed
    for (int e4 = tid; e4 < 4096; e4 += 256) {
        int e = e4 * 4;
        int b = e >> 9, k = e & 511;
        float4 v = *(const float4*)(h_in + e);
        float m = mds[b];
        Hs[(k + 0) * 33 + b] = v.x * m;
        Hs[(k + 1) * 33 + b] = v.y * m;
        Hs[(k + 2) * 33 + b] = v.z * m;
        Hs[(k + 3) * 33 + b] = v.w * m;
    }
    __syncthreads();

    int b = threadIdx.x;
    int j = blockIdx.x * 8 + threadIdx.y;
    int row = t * 32 + b;
    const float* g_base = gx + (size_t)row * 2048;
    float ai = g_base[j];
    float af = g_base[512 + j];
    float ag = g_base[1024 + j];
    float ao = g_base[1536 + j];
    const float* wi = whh + (size_t)j * 512;
    const float* wf = wi + 512 * 512;
    const float* wg = wi + 1024 * 512;
    const float* wo = wi + 1536 * 512;

    for (int k = 0; k < 512; k += 4) {
        float4 w0 = *(const float4*)(wi + k);
        float4 w1 = *(const float4*)(wf + k);
        float4 w2 = *(const float4*)(wg + k);
        float4 w3 = *(const float4*)(wo + k);
        float h0v = Hs[(k + 0) * 33 + b];
        float h1v = Hs[(k + 1) * 33 + b];
        float h2v = Hs[(k + 2) * 33 + b];
        float h3v = Hs[(k + 3) * 33 + b];
        ai += h0v * w0.x + h1v * w0.y + h2v * w0.z + h3v * w0.w;
        af += h0v * w1.x + h1v * w1.y + h2v * w1.z + h3v * w1.w;
        ag += h0v * w2.x + h1v * w2.y + h2v * w2.z + h3v * w2.w;
        ao += h0v * w3.x + h1v * w3.y + h2v * w3.z + h3v * w3.w;
    }

    float md = mds[b];
    float cp = c_buf[b * 512 + j] * md;
    float si = 1.f / (1.f + expf(-ai));
    float sf = 1.f / (1.f + expf(-af));
    float so = 1.f / (1.f + expf(-ao));
    float cn = sf * cp + si * tanhf(ag);
    float hn = so * tanhf(cn);
    c_buf[b * 512 + j] = cn;
    h_out[b * 512 + j] = hn;
    feat[(size_t)row * 512 + j] = hn;
    if (hN) {
        hN[b * 512 + j] = hn;
        cN[b * 512 + j] = cn;
    }
}

// ---------------------------------------------------------------------------
extern "C" void kernel_launch(void* const* d_in, const int* in_sizes, int n_in,
                              void* d_out, int out_size, void* d_ws, size_t ws_size,
                              hipStream_t stream) {
    const float* x    = (const float*)d_in[0];
    const float* done = (const float*)d_in[1];
    const float* h0   = (const float*)d_in[2];
    const float* c0   = (const float*)d_in[3];
    const float* c1w  = (const float*)d_in[4];
    const float* c1b  = (const float*)d_in[5];
    const float* c2w  = (const float*)d_in[6];
    const float* c2b  = (const float*)d_in[7];
    const float* c3w  = (const float*)d_in[8];
    const float* c3b  = (const float*)d_in[9];
    const float* fc1w = (const float*)d_in[10];
    const float* fc1b = (const float*)d_in[11];
    const float* fc2w = (const float*)d_in[12];
    const float* fc2b = (const float*)d_in[13];
    const float* wih  = (const float*)d_in[14];
    const float* whh  = (const float*)d_in[15];
    const float* bih  = (const float*)d_in[16];
    const float* bhh  = (const float*)d_in[17];
    const float* dfw  = (const float*)d_in[18];
    const float* dfb  = (const float*)d_in[19];
    const float* dw   = (const float*)d_in[20];
    const float* db   = (const float*)d_in[21];
    float* out = (float*)d_out;

    const size_t CONV_ELEMS = 57802752;        // 2048*4*84*84
    float* bufA = (float*)d_ws;
    float* bufB = bufA + CONV_ELEMS;
    // small buffers alias bufB (bufB is dead once conv3 has consumed it)
    float* hfc1  = bufB;                       // [2048,512]
    float* hfc2  = hfc1 + 1048576;             // [2048,512]
    float* gx    = hfc2 + 1048576;             // [2048,2048]
    float* feat  = gx + 4194304;               // [2048,512]
    float* dfeat = feat + 1048576;             // [2048,128]
    float* hA    = dfeat + 262144;             // [32,512]
    float* hB    = hA + 16384;                 // [32,512]
    float* cb    = hB + 16384;                 // [32,512]

    // --- conv stack ---
    int convThreads = 2048 * 84 * 84;          // 14,450,688
    dim3 cgrid((convThreads + 255) / 256);
    conv_lrelu_kernel<5><<<cgrid, 256, 0, stream>>>(x,    c1w, c1b, bufA, convThreads);
    conv_lrelu_kernel<3><<<cgrid, 256, 0, stream>>>(bufA, c2w, c2b, bufB, convThreads);
    conv_lrelu_kernel<3><<<cgrid, 256, 0, stream>>>(bufB, c3w, c3b, bufA, convThreads);

    // --- MLP ---
    gemm_nt_kernel<true, false><<<dim3(512 / 32, 2048 / 64), 256, 0, stream>>>(
        bufA, fc1w, fc1b, nullptr, hfc1, 2048, 512, 28224);
    gemm_nt_kernel<true, false><<<dim3(512 / 32, 2048 / 64), 256, 0, stream>>>(
        hfc1, fc2w, fc2b, nullptr, hfc2, 2048, 512, 512);

    // --- x-part of LSTM gates for all timesteps ---
    gemm_nt_kernel<false, true><<<dim3(2048 / 32, 2048 / 64), 256, 0, stream>>>(
        hfc2, wih, bih, bhh, gx, 2048, 2048, 512);

    // --- LSTM scan ---
    init_state_kernel<<<dim3(64), 256, 0, stream>>>(h0, c0, hA, cb);
    float* hin = hA;
    float* hout = hB;
    for (int t = 0; t < 64; ++t) {
        float* hNp = (t == 63) ? (out + 131072) : nullptr;
        float* cNp = (t == 63) ? (out + 131072 + 16384) : nullptr;
        lstm_step_kernel<<<dim3(64), dim3(32, 8), 0, stream>>>(
            gx, done, whh, hin, hout, cb, feat, hNp, cNp, t);
        float* tmp = hin; hin = hout; hout = tmp;
    }

    // --- discriminator head ---
    gemm_nt_kernel<true, false><<<dim3(128 / 32, 2048 / 64), 256, 0, stream>>>(
        feat, dfw, dfb, nullptr, dfeat, 2048, 128, 512);
    gemm_nt_kernel<false, false><<<dim3(64 / 32, 2048 / 64), 256, 0, stream>>>(
        dfeat, dw, db, nullptr, out, 2048, 64, 128);
}

// Round 2
// 2832.591 us; speedup vs baseline: 1.9226x; 1.9226x over previous
//
#include <hip/hip_runtime.h>
#include <math.h>

#define SLOPE 0.01f

typedef __attribute__((ext_vector_type(8))) short bf16x8;
typedef __attribute__((ext_vector_type(4))) float f32x4;

__device__ __forceinline__ float lrelu(float x) {
    return x > 0.f ? x : SLOPE * x;
}

__device__ __forceinline__ unsigned short f2bf(float f) {
    unsigned int u = __float_as_uint(f);
    u += 0x7fffu + ((u >> 16) & 1u);
    return (unsigned short)(u >> 16);
}

// ---------------------------------------------------------------------------
// f32 -> bf16 conversion, 4 elems/thread (n % 4 == 0 for all our tensors)
// ---------------------------------------------------------------------------
__global__ void cvt_bf16_kernel(const float* __restrict__ src,
                                unsigned short* __restrict__ dst, int n4) {
    int i = blockIdx.x * blockDim.x + threadIdx.x;
    if (i >= n4) return;
    float4 v = ((const float4*)src)[i];
    uint2 o;
    o.x = (unsigned)f2bf(v.x) | ((unsigned)f2bf(v.y) << 16);
    o.y = (unsigned)f2bf(v.z) | ((unsigned)f2bf(v.w) << 16);
    ((uint2*)dst)[i] = o;
}

// ---------------------------------------------------------------------------
// Conv 4->4, SAME, kernel K, fused bias + LeakyReLU. f32 in; f32 or bf16 out.
// ---------------------------------------------------------------------------
template<int K, bool OUTBF>
__global__ void conv_lrelu_kernel(const float* __restrict__ in,
                                  const float* __restrict__ w,
                                  const float* __restrict__ b,
                                  void* __restrict__ out_v, int total) {
    constexpr int PAD = K / 2;
    __shared__ float ws[16 * K * K];
    __shared__ float bs[4];
    int tid = threadIdx.x;
    for (int i = tid; i < 16 * K * K; i += blockDim.x) ws[i] = w[i];
    if (tid < 4) bs[tid] = b[tid];
    __syncthreads();

    int idx = blockIdx.x * blockDim.x + tid;
    if (idx >= total) return;
    int ww_ = idx % 84;
    int t   = idx / 84;
    int hh  = t % 84;
    int n   = t / 84;

    float acc0 = bs[0], acc1 = bs[1], acc2 = bs[2], acc3 = bs[3];
    const float* inN = in + (size_t)n * (4 * 84 * 84);
    #pragma unroll
    for (int ci = 0; ci < 4; ++ci) {
        #pragma unroll
        for (int kh = 0; kh < K; ++kh) {
            int ih = hh + kh - PAD;
            if ((unsigned)ih >= 84u) continue;
            #pragma unroll
            for (int kw = 0; kw < K; ++kw) {
                int iw = ww_ + kw - PAD;
                if ((unsigned)iw >= 84u) continue;
                float v = inN[(ci * 84 + ih) * 84 + iw];
                acc0 += v * ws[((0 * 4 + ci) * K + kh) * K + kw];
                acc1 += v * ws[((1 * 4 + ci) * K + kh) * K + kw];
                acc2 += v * ws[((2 * 4 + ci) * K + kh) * K + kw];
                acc3 += v * ws[((3 * 4 + ci) * K + kh) * K + kw];
            }
        }
    }
    size_t o0 = (size_t)n * (4 * 84 * 84) + (size_t)(0 * 84 + hh) * 84 + ww_;
    const size_t cs = 84 * 84;
    if (OUTBF) {
        unsigned short* o = (unsigned short*)out_v;
        o[o0 + 0 * cs] = f2bf(lrelu(acc0));
        o[o0 + 1 * cs] = f2bf(lrelu(acc1));
        o[o0 + 2 * cs] = f2bf(lrelu(acc2));
        o[o0 + 3 * cs] = f2bf(lrelu(acc3));
    } else {
        float* o = (float*)out_v;
        o[o0 + 0 * cs] = lrelu(acc0);
        o[o0 + 1 * cs] = lrelu(acc1);
        o[o0 + 2 * cs] = lrelu(acc2);
        o[o0 + 3 * cs] = lrelu(acc3);
    }
}

// ---------------------------------------------------------------------------
// bf16 MFMA GEMM (NT): C[M,N] = A[M,K] * B[N,K]^T + bias (+bias2), opt lrelu.
// A,B bf16 (K-contiguous). BM=BN=64, BK=32, 256 thr = 4 waves, each wave a
// 32x32 quadrant = 2x2 frags of mfma_f32_16x16x32_bf16. LDS padded to 40
// bf16/row (80B stride -> 2-way bank aliasing, free).
// Requires M%64==0, N%64==0, K%32==0.
// ---------------------------------------------------------------------------
template<bool DO_LRELU, bool BIAS2, bool OUTBF>
__global__ void gemm_bf16_kernel(const unsigned short* __restrict__ A,
                                 const unsigned short* __restrict__ B,
                                 const float* __restrict__ bias,
                                 const float* __restrict__ bias2,
                                 void* __restrict__ Cout,
                                 int M, int N, int K) {
    __shared__ unsigned short As[64][40];
    __shared__ unsigned short Bs[64][40];
    int tid = threadIdx.x;
    int rowBase = blockIdx.y * 64;
    int colBase = blockIdx.x * 64;

    int wave = tid >> 6;
    int l    = tid & 63;
    int wr = wave >> 1, wc = wave & 1;
    int lane16 = l & 15;
    int kb = (l >> 4) * 8;

    int sr = tid >> 2;            // 0..63
    int sk = (tid & 3) * 8;       // 0,8,16,24
    const unsigned short* Ap = A + (size_t)(rowBase + sr) * K + sk;
    const unsigned short* Bp = B + (size_t)(colBase + sr) * K + sk;

    f32x4 acc[2][2] = {};

    for (int k0 = 0; k0 < K; k0 += 32) {
        float4 av = *(const float4*)(Ap + k0);
        float4 bv = *(const float4*)(Bp + k0);
        __syncthreads();
        *(float4*)(&As[sr][sk]) = av;
        *(float4*)(&Bs[sr][sk]) = bv;
        __syncthreads();
        bf16x8 a0 = *(const bf16x8*)(&As[wr * 32 + lane16][kb]);
        bf16x8 a1 = *(const bf16x8*)(&As[wr * 32 + 16 + lane16][kb]);
        bf16x8 b0 = *(const bf16x8*)(&Bs[wc * 32 + lane16][kb]);
        bf16x8 b1 = *(const bf16x8*)(&Bs[wc * 32 + 16 + lane16][kb]);
        acc[0][0] = __builtin_amdgcn_mfma_f32_16x16x32_bf16(a0, b0, acc[0][0], 0, 0, 0);
        acc[0][1] = __builtin_amdgcn_mfma_f32_16x16x32_bf16(a0, b1, acc[0][1], 0, 0, 0);
        acc[1][0] = __builtin_amdgcn_mfma_f32_16x16x32_bf16(a1, b0, acc[1][0], 0, 0, 0);
        acc[1][1] = __builtin_amdgcn_mfma_f32_16x16x32_bf16(a1, b1, acc[1][1], 0, 0, 0);
    }

    // C layout: col = lane&15, row = (lane>>4)*4 + reg
    int crow0 = rowBase + wr * 32 + (l >> 4) * 4;
    int ccol0 = colBase + wc * 32 + lane16;
    float bsv[2];
    #pragma unroll
    for (int j = 0; j < 2; ++j) {
        bsv[j] = bias[ccol0 + j * 16];
        if (BIAS2) bsv[j] += bias2[ccol0 + j * 16];
    }
    #pragma unroll
    for (int i = 0; i < 2; ++i) {
        #pragma unroll
        for (int r = 0; r < 4; ++r) {
            int row = crow0 + i * 16 + r;
            #pragma unroll
            for (int j = 0; j < 2; ++j) {
                float v = acc[i][j][r] + bsv[j];
                if (DO_LRELU) v = lrelu(v);
                size_t off = (size_t)row * N + ccol0 + j * 16;
                if (OUTBF) ((unsigned short*)Cout)[off] = f2bf(v);
                else       ((float*)Cout)[off] = v;
            }
        }
    }
}

// ---------------------------------------------------------------------------
// LSTM init: H (bf16 [32][512]) from h0; cT (f32 [512][32]) = c0^T
// ---------------------------------------------------------------------------
__global__ void lstm_init_kernel(const float* __restrict__ h0,
                                 const float* __restrict__ c0,
                                 unsigned short* __restrict__ H,
                                 float* __restrict__ cT) {
    int i = blockIdx.x * blockDim.x + threadIdx.x;
    if (i >= 16384) return;
    int b = i >> 9, j = i & 511;
    H[i] = f2bf(h0[i]);
    cT[j * 32 + b] = c0[i];
}

// ---------------------------------------------------------------------------
// One LSTM step, MFMA. Grid 64 blocks x 64 threads (1 wave).
// Wave (jt = blk>>1, bt = blk&1) computes C[16 j x 16 b] for all 4 gates:
// gates_hh = Whh_bf16 . H^T. Mask applied in epilogue (m * acc == Whh.(m*h)).
// Pointwise update fully in-register (lane owns i,f,g,o of its (j,b)).
// ---------------------------------------------------------------------------
__global__ void lstm_step_kernel(const unsigned short* __restrict__ whh_b, // [2048][512]
                                 const unsigned short* __restrict__ Hin,   // [32][512]
                                 unsigned short* __restrict__ Hout,        // [32][512]
                                 float* __restrict__ cT,                   // [512][32]
                                 const float* __restrict__ gx,             // [2048][2048]
                                 const float* __restrict__ done,
                                 unsigned short* __restrict__ feat,        // [2048][512]
                                 float* __restrict__ hN,                   // null unless t==63
                                 float* __restrict__ cN,
                                 int t) {
    int l  = threadIdx.x;
    int jt = blockIdx.x >> 1;
    int bt = blockIdx.x & 1;
    int lane16 = l & 15;
    int khi = l >> 4;
    int b = bt * 16 + lane16;

    f32x4 acc[4] = {};
    const unsigned short* Hrow = Hin + b * 512 + khi * 8;
    const unsigned short* Wbase = whh_b + (size_t)(jt * 16 + lane16) * 512 + khi * 8;

    #pragma unroll 4
    for (int k0 = 0; k0 < 512; k0 += 32) {
        bf16x8 hb = *(const bf16x8*)(Hrow + k0);
        #pragma unroll
        for (int g = 0; g < 4; ++g) {
            bf16x8 wb = *(const bf16x8*)(Wbase + (size_t)g * 512 * 512 + k0);
            acc[g] = __builtin_amdgcn_mfma_f32_16x16x32_bf16(wb, hb, acc[g], 0, 0, 0);
        }
    }

    // epilogue: lane holds rows j0..j0+3 (j0 = jt*16 + khi*4), col b
    float m = 1.0f - done[t * 32 + b];
    int j0 = jt * 16 + khi * 4;
    const float* gbase = gx + (size_t)(t * 32 + b) * 2048;
    float4 gxi = *(const float4*)(gbase + 0 * 512 + j0);
    float4 gxf = *(const float4*)(gbase + 1 * 512 + j0);
    float4 gxg = *(const float4*)(gbase + 2 * 512 + j0);
    float4 gxo = *(const float4*)(gbase + 3 * 512 + j0);

    float hnew[4], cnew[4];
    #pragma unroll
    for (int r = 0; r < 4; ++r) {
        float ai = ((const float*)&gxi)[r] + m * acc[0][r];
        float af = ((const float*)&gxf)[r] + m * acc[1][r];
        float ag = ((const float*)&gxg)[r] + m * acc[2][r];
        float ao = ((const float*)&gxo)[r] + m * acc[3][r];
        float cp = cT[(j0 + r) * 32 + b] * m;
        float si = 1.f / (1.f + __expf(-ai));
        float sf = 1.f / (1.f + __expf(-af));
        float so = 1.f / (1.f + __expf(-ao));
        float cn = sf * cp + si * tanhf(ag);
        float hn = so * tanhf(cn);
        cT[(j0 + r) * 32 + b] = cn;
        cnew[r] = cn;
        hnew[r] = hn;
    }
    unsigned int p01 = (unsigned)f2bf(hnew[0]) | ((unsigned)f2bf(hnew[1]) << 16);
    unsigned int p23 = (unsigned)f2bf(hnew[2]) | ((unsigned)f2bf(hnew[3]) << 16);
    *(unsigned int*)(Hout + b * 512 + j0)     = p01;
    *(unsigned int*)(Hout + b * 512 + j0 + 2) = p23;
    *(unsigned int*)(feat + (size_t)(t * 32 + b) * 512 + j0)     = p01;
    *(unsigned int*)(feat + (size_t)(t * 32 + b) * 512 + j0 + 2) = p23;
    if (hN) {
        #pragma unroll
        for (int r = 0; r < 4; ++r) {
            hN[b * 512 + j0 + r] = hnew[r];
            cN[b * 512 + j0 + r] = cnew[r];
        }
    }
}

// ---------------------------------------------------------------------------
extern "C" void kernel_launch(void* const* d_in, const int* in_sizes, int n_in,
                              void* d_out, int out_size, void* d_ws, size_t ws_size,
                              hipStream_t stream) {
    const float* x    = (const float*)d_in[0];
    const float* done = (const float*)d_in[1];
    const float* h0   = (const float*)d_in[2];
    const float* c0   = (const float*)d_in[3];
    const float* c1w  = (const float*)d_in[4];
    const float* c1b  = (const float*)d_in[5];
    const float* c2w  = (const float*)d_in[6];
    const float* c2b  = (const float*)d_in[7];
    const float* c3w  = (const float*)d_in[8];
    const float* c3b  = (const float*)d_in[9];
    const float* fc1w = (const float*)d_in[10];
    const float* fc1b = (const float*)d_in[11];
    const float* fc2w = (const float*)d_in[12];
    const float* fc2b = (const float*)d_in[13];
    const float* wih  = (const float*)d_in[14];
    const float* whh  = (const float*)d_in[15];
    const float* bih  = (const float*)d_in[16];
    const float* bhh  = (const float*)d_in[17];
    const float* dfw  = (const float*)d_in[18];
    const float* dfb  = (const float*)d_in[19];
    const float* dw   = (const float*)d_in[20];
    const float* db   = (const float*)d_in[21];
    float* out = (float*)d_out;

    const size_t CONV_ELEMS = 57802752;            // 2048*4*84*84
    float* bufA = (float*)d_ws;                    // conv ping (f32)
    float* bufB = bufA + CONV_ELEMS;               // conv pong (f32)
    unsigned short* conv_out_b = (unsigned short*)bufA;  // conv3 writes bf16 into bufA

    // small-buffer region aliases bufB (dead after conv3 has read it)
    char* S = (char*)bufB;
    unsigned short* fc1w_b = (unsigned short*)S;                 S += 28901376;
    unsigned short* fc2w_b = (unsigned short*)S;                 S += 524288;
    unsigned short* wih_b  = (unsigned short*)S;                 S += 2097152;
    unsigned short* whh_b  = (unsigned short*)S;                 S += 2097152;
    unsigned short* dfw_b  = (unsigned short*)S;                 S += 131072;
    unsigned short* dw_b   = (unsigned short*)S;                 S += 16384;
    unsigned short* hfc1_b = (unsigned short*)S;                 S += 2097152;
    unsigned short* hfc2_b = (unsigned short*)S;                 S += 2097152;
    float*          gx     = (float*)S;                          S += 16777216;
    unsigned short* feat_b = (unsigned short*)S;                 S += 2097152;
    unsigned short* dfeat_b= (unsigned short*)S;                 S += 524288;
    unsigned short* HA     = (unsigned short*)S;                 S += 32768;
    unsigned short* HB     = (unsigned short*)S;                 S += 32768;
    float*          cT     = (float*)S;                          S += 65536;

    // --- conv stack (f32, conv3 emits bf16) ---
    int convThreads = 2048 * 84 * 84;
    dim3 cgrid((convThreads + 255) / 256);
    conv_lrelu_kernel<5, false><<<cgrid, 256, 0, stream>>>(x,    c1w, c1b, bufA, convThreads);
    conv_lrelu_kernel<3, false><<<cgrid, 256, 0, stream>>>(bufA, c2w, c2b, bufB, convThreads);
    conv_lrelu_kernel<3, true ><<<cgrid, 256, 0, stream>>>(bufB, c3w, c3b, conv_out_b, convThreads);

    // --- weight conversions (after conv3 has consumed bufB) ---
    auto cvt = [&](const float* s, unsigned short* d, int n) {
        int n4 = n / 4;
        cvt_bf16_kernel<<<(n4 + 255) / 256, 256, 0, stream>>>(s, d, n4);
    };
    cvt(fc1w, fc1w_b, 14450688);
    cvt(fc2w, fc2w_b, 262144);
    cvt(wih,  wih_b,  1048576);
    cvt(whh,  whh_b,  1048576);
    cvt(dfw,  dfw_b,  65536);
    cvt(dw,   dw_b,   8192);

    // --- MLP (bf16 MFMA) ---
    gemm_bf16_kernel<true, false, true><<<dim3(512 / 64, 2048 / 64), 256, 0, stream>>>(
        conv_out_b, fc1w_b, fc1b, nullptr, hfc1_b, 2048, 512, 28224);
    gemm_bf16_kernel<true, false, true><<<dim3(512 / 64, 2048 / 64), 256, 0, stream>>>(
        hfc1_b, fc2w_b, fc2b, nullptr, hfc2_b, 2048, 512, 512);

    // --- x-part of LSTM gates (f32 out) ---
    gemm_bf16_kernel<false, true, false><<<dim3(2048 / 64, 2048 / 64), 256, 0, stream>>>(
        hfc2_b, wih_b, bih, bhh, gx, 2048, 2048, 512);

    // --- LSTM scan ---
    lstm_init_kernel<<<dim3(64), 256, 0, stream>>>(h0, c0, HA, cT);
    unsigned short* hin = HA;
    unsigned short* hout = HB;
    for (int t = 0; t < 64; ++t) {
        float* hNp = (t == 63) ? (out + 131072) : nullptr;
        float* cNp = (t == 63) ? (out + 131072 + 16384) : nullptr;
        lstm_step_kernel<<<dim3(64), dim3(64), 0, stream>>>(
            whh_b, hin, hout, cT, gx, done, feat_b, hNp, cNp, t);
        unsigned short* tmp = hin; hin = hout; hout = tmp;
    }

    // --- discriminator head ---
    gemm_bf16_kernel<true, false, true><<<dim3(128 / 64, 2048 / 64), 256, 0, stream>>>(
        feat_b, dfw_b, dfb, nullptr, dfeat_b, 2048, 128, 512);
    gemm_bf16_kernel<false, false, false><<<dim3(64 / 64, 2048 / 64), 256, 0, stream>>>(
        dfeat_b, dw_b, db, nullptr, out, 2048, 64, 128);
}

// Round 3
// 1802.167 us; speedup vs baseline: 3.0219x; 1.5718x over previous
//
#include <hip/hip_runtime.h>
#include <math.h>

#define SLOPE 0.01f

typedef __attribute__((ext_vector_type(8))) short bf16x8;
typedef __attribute__((ext_vector_type(4))) float f32x4;
typedef unsigned short ushort_t;

__device__ __forceinline__ float lrelu(float x) {
    return x > 0.f ? x : SLOPE * x;
}

__device__ __forceinline__ unsigned short f2bf(float f) {
    unsigned int u = __float_as_uint(f);
    u += 0x7fffu + ((u >> 16) & 1u);
    return (unsigned short)(u >> 16);
}

__device__ __forceinline__ float bf2f(unsigned short u) {
    return __uint_as_float((unsigned int)u << 16);
}

// ---------------------------------------------------------------------------
// f32 -> bf16 conversion, 4 elems/thread
// ---------------------------------------------------------------------------
__global__ void cvt_bf16_kernel(const float* __restrict__ src,
                                unsigned short* __restrict__ dst, int n4) {
    int i = blockIdx.x * blockDim.x + threadIdx.x;
    if (i >= n4) return;
    float4 v = ((const float4*)src)[i];
    uint2 o;
    o.x = (unsigned)f2bf(v.x) | ((unsigned)f2bf(v.y) << 16);
    o.y = (unsigned)f2bf(v.z) | ((unsigned)f2bf(v.w) << 16);
    ((uint2*)dst)[i] = o;
}

// ---------------------------------------------------------------------------
// LDS-tiled conv 4->4, SAME, kernel K, fused bias+LeakyReLU.
// Grid: (2048 images, 7 row-tiles). Block 256 threads.
// Stage [4ci][TILE_H+2*HALO][88] input strip (zero-filled halo) + reordered
// weights in LDS. Each thread: 12 rows x 21 col-groups; computes 4 consecutive
// w outputs x 4 co (16 accum). Inner loop branch-free, vector LDS reads.
// ---------------------------------------------------------------------------
template<int K, bool INBF, bool OUTBF>
__global__ __launch_bounds__(256) void conv_tile_kernel(
        const void* __restrict__ in_v,
        const float* __restrict__ w,
        const float* __restrict__ b,
        void* __restrict__ out_v) {
    constexpr int HALO = K / 2;
    constexpr int TILE_H = 12;
    constexpr int SH = TILE_H + 2 * HALO;     // 16 (K=5), 14 (K=3)
    constexpr int SW = 88;                    // 84 + halo, padded
    __shared__ float smem[4][SH][SW];
    __shared__ float wle[4][K][4][K + 1];     // [ci][kh][co][kw] (+1 pad)
    __shared__ float bs[4];

    int tid = threadIdx.x;
    int n = blockIdx.x;
    int row0 = blockIdx.y * TILE_H;
    const size_t imgOff = (size_t)n * (4 * 84 * 84);

    // stage weights reordered: w[((co*4+ci)*K+kh)*K+kw] -> wle[ci][kh][co][kw]
    for (int i = tid; i < 16 * K * K; i += 256) {
        int kw = i % K; int t2 = i / K;
        int kh = t2 % K; int t3 = t2 / K;
        int ci = t3 & 3;  int co = t3 >> 2;
        wle[ci][kh][co][kw] = w[i];
    }
    if (tid < 4) bs[tid] = b[tid];

    // stage input strip with zero-filled halo
    for (int i = tid; i < 4 * SH * SW; i += 256) {
        int c = i % SW; int t2 = i / SW;
        int r = t2 % SH; int ci = t2 / SH;
        int ih = row0 + r - HALO;
        int iw = c - HALO;
        float v = 0.f;
        if ((unsigned)ih < 84u && (unsigned)iw < 84u) {
            size_t off = imgOff + ((size_t)ci * 84 + ih) * 84 + iw;
            v = INBF ? bf2f(((const ushort_t*)in_v)[off])
                     : ((const float*)in_v)[off];
        }
        smem[ci][r][c] = v;
    }
    __syncthreads();

    if (tid >= 252) return;
    int r  = tid / 21;            // 0..11
    int w0 = (tid % 21) * 4;      // 0..80

    float acc[4][4];
    #pragma unroll
    for (int co = 0; co < 4; ++co)
        #pragma unroll
        for (int dw = 0; dw < 4; ++dw) acc[co][dw] = bs[co];

    #pragma unroll
    for (int ci = 0; ci < 4; ++ci) {
        #pragma unroll
        for (int kh = 0; kh < K; ++kh) {
            float vals[K + 3];
            float4 v0 = *(const float4*)&smem[ci][r + kh][w0];
            vals[0] = v0.x; vals[1] = v0.y; vals[2] = v0.z; vals[3] = v0.w;
            if (K == 5) {
                float4 v1 = *(const float4*)&smem[ci][r + kh][w0 + 4];
                vals[4] = v1.x; vals[5] = v1.y; vals[6] = v1.z; vals[7] = v1.w;
            } else {
                float2 v1 = *(const float2*)&smem[ci][r + kh][w0 + 4];
                vals[4] = v1.x; vals[5] = v1.y;
            }
            #pragma unroll
            for (int co = 0; co < 4; ++co) {
                #pragma unroll
                for (int kw = 0; kw < K; ++kw) {
                    float wv = wle[ci][kh][co][kw];
                    #pragma unroll
                    for (int dw = 0; dw < 4; ++dw)
                        acc[co][dw] += vals[kw + dw] * wv;
                }
            }
        }
    }

    int oh = row0 + r;
    #pragma unroll
    for (int co = 0; co < 4; ++co) {
        size_t off = imgOff + ((size_t)co * 84 + oh) * 84 + w0;
        float o0 = lrelu(acc[co][0]);
        float o1 = lrelu(acc[co][1]);
        float o2 = lrelu(acc[co][2]);
        float o3 = lrelu(acc[co][3]);
        if (OUTBF) {
            uint2 p;
            p.x = (unsigned)f2bf(o0) | ((unsigned)f2bf(o1) << 16);
            p.y = (unsigned)f2bf(o2) | ((unsigned)f2bf(o3) << 16);
            *(uint2*)((ushort_t*)out_v + off) = p;
        } else {
            *(float4*)((float*)out_v + off) = make_float4(o0, o1, o2, o3);
        }
    }
}

// ---------------------------------------------------------------------------
// bf16 MFMA GEMM (NT): C[M,N] = A[M,K] * B[N,K]^T + bias (+bias2), opt lrelu.
// BM=BN=64, BK=32, 4 waves, each a 32x32 quadrant (2x2 frags 16x16x32).
// ---------------------------------------------------------------------------
template<bool DO_LRELU, bool BIAS2, bool OUTBF>
__global__ void gemm_bf16_kernel(const unsigned short* __restrict__ A,
                                 const unsigned short* __restrict__ B,
                                 const float* __restrict__ bias,
                                 const float* __restrict__ bias2,
                                 void* __restrict__ Cout,
                                 int M, int N, int K) {
    __shared__ unsigned short As[64][40];
    __shared__ unsigned short Bs[64][40];
    int tid = threadIdx.x;
    int rowBase = blockIdx.y * 64;
    int colBase = blockIdx.x * 64;

    int wave = tid >> 6;
    int l    = tid & 63;
    int wr = wave >> 1, wc = wave & 1;
    int lane16 = l & 15;
    int kb = (l >> 4) * 8;

    int sr = tid >> 2;
    int sk = (tid & 3) << 3;
    const unsigned short* Ap = A + (size_t)(rowBase + sr) * K + sk;
    const unsigned short* Bp = B + (size_t)(colBase + sr) * K + sk;

    f32x4 acc[2][2] = {};

    for (int k0 = 0; k0 < K; k0 += 32) {
        float4 av = *(const float4*)(Ap + k0);
        float4 bv = *(const float4*)(Bp + k0);
        __syncthreads();
        *(float4*)(&As[sr][sk]) = av;
        *(float4*)(&Bs[sr][sk]) = bv;
        __syncthreads();
        bf16x8 a0 = *(const bf16x8*)(&As[wr * 32 + lane16][kb]);
        bf16x8 a1 = *(const bf16x8*)(&As[wr * 32 + 16 + lane16][kb]);
        bf16x8 b0 = *(const bf16x8*)(&Bs[wc * 32 + lane16][kb]);
        bf16x8 b1 = *(const bf16x8*)(&Bs[wc * 32 + 16 + lane16][kb]);
        acc[0][0] = __builtin_amdgcn_mfma_f32_16x16x32_bf16(a0, b0, acc[0][0], 0, 0, 0);
        acc[0][1] = __builtin_amdgcn_mfma_f32_16x16x32_bf16(a0, b1, acc[0][1], 0, 0, 0);
        acc[1][0] = __builtin_amdgcn_mfma_f32_16x16x32_bf16(a1, b0, acc[1][0], 0, 0, 0);
        acc[1][1] = __builtin_amdgcn_mfma_f32_16x16x32_bf16(a1, b1, acc[1][1], 0, 0, 0);
    }

    int crow0 = rowBase + wr * 32 + (l >> 4) * 4;
    int ccol0 = colBase + wc * 32 + lane16;
    float bsv[2];
    #pragma unroll
    for (int j = 0; j < 2; ++j) {
        bsv[j] = bias[ccol0 + j * 16];
        if (BIAS2) bsv[j] += bias2[ccol0 + j * 16];
    }
    #pragma unroll
    for (int i = 0; i < 2; ++i) {
        #pragma unroll
        for (int r = 0; r < 4; ++r) {
            int row = crow0 + i * 16 + r;
            #pragma unroll
            for (int j = 0; j < 2; ++j) {
                float v = acc[i][j][r] + bsv[j];
                if (DO_LRELU) v = lrelu(v);
                size_t off = (size_t)row * N + ccol0 + j * 16;
                if (OUTBF) ((unsigned short*)Cout)[off] = f2bf(v);
                else       ((float*)Cout)[off] = v;
            }
        }
    }
}

// ---------------------------------------------------------------------------
// LSTM init: H (bf16 [32][512]) from h0; cT (f32 [512][32]) = c0^T
// ---------------------------------------------------------------------------
__global__ void lstm_init_kernel(const float* __restrict__ h0,
                                 const float* __restrict__ c0,
                                 unsigned short* __restrict__ H,
                                 float* __restrict__ cT) {
    int i = blockIdx.x * blockDim.x + threadIdx.x;
    if (i >= 16384) return;
    int b = i >> 9, j = i & 511;
    H[i] = f2bf(h0[i]);
    cT[j * 32 + b] = c0[i];
}

// ---------------------------------------------------------------------------
// One LSTM step, MFMA. Grid 64 blocks x 64 threads (1 wave).
// ---------------------------------------------------------------------------
__global__ void lstm_step_kernel(const unsigned short* __restrict__ whh_b,
                                 const unsigned short* __restrict__ Hin,
                                 unsigned short* __restrict__ Hout,
                                 float* __restrict__ cT,
                                 const float* __restrict__ gx,
                                 const float* __restrict__ done,
                                 unsigned short* __restrict__ feat,
                                 float* __restrict__ hN,
                                 float* __restrict__ cN,
                                 int t) {
    int l  = threadIdx.x;
    int jt = blockIdx.x >> 1;
    int bt = blockIdx.x & 1;
    int lane16 = l & 15;
    int khi = l >> 4;
    int b = bt * 16 + lane16;

    f32x4 acc[4] = {};
    const unsigned short* Hrow = Hin + b * 512 + khi * 8;
    const unsigned short* Wbase = whh_b + (size_t)(jt * 16 + lane16) * 512 + khi * 8;

    #pragma unroll 4
    for (int k0 = 0; k0 < 512; k0 += 32) {
        bf16x8 hb = *(const bf16x8*)(Hrow + k0);
        #pragma unroll
        for (int g = 0; g < 4; ++g) {
            bf16x8 wb = *(const bf16x8*)(Wbase + (size_t)g * 512 * 512 + k0);
            acc[g] = __builtin_amdgcn_mfma_f32_16x16x32_bf16(wb, hb, acc[g], 0, 0, 0);
        }
    }

    float m = 1.0f - done[t * 32 + b];
    int j0 = jt * 16 + khi * 4;
    const float* gbase = gx + (size_t)(t * 32 + b) * 2048;
    float4 gxi = *(const float4*)(gbase + 0 * 512 + j0);
    float4 gxf = *(const float4*)(gbase + 1 * 512 + j0);
    float4 gxg = *(const float4*)(gbase + 2 * 512 + j0);
    float4 gxo = *(const float4*)(gbase + 3 * 512 + j0);

    float hnew[4], cnew[4];
    #pragma unroll
    for (int r = 0; r < 4; ++r) {
        float ai = ((const float*)&gxi)[r] + m * acc[0][r];
        float af = ((const float*)&gxf)[r] + m * acc[1][r];
        float ag = ((const float*)&gxg)[r] + m * acc[2][r];
        float ao = ((const float*)&gxo)[r] + m * acc[3][r];
        float cp = cT[(j0 + r) * 32 + b] * m;
        float si = 1.f / (1.f + __expf(-ai));
        float sf = 1.f / (1.f + __expf(-af));
        float so = 1.f / (1.f + __expf(-ao));
        float cn = sf * cp + si * tanhf(ag);
        float hn = so * tanhf(cn);
        cT[(j0 + r) * 32 + b] = cn;
        cnew[r] = cn;
        hnew[r] = hn;
    }
    unsigned int p01 = (unsigned)f2bf(hnew[0]) | ((unsigned)f2bf(hnew[1]) << 16);
    unsigned int p23 = (unsigned)f2bf(hnew[2]) | ((unsigned)f2bf(hnew[3]) << 16);
    *(unsigned int*)(Hout + b * 512 + j0)     = p01;
    *(unsigned int*)(Hout + b * 512 + j0 + 2) = p23;
    *(unsigned int*)(feat + (size_t)(t * 32 + b) * 512 + j0)     = p01;
    *(unsigned int*)(feat + (size_t)(t * 32 + b) * 512 + j0 + 2) = p23;
    if (hN) {
        #pragma unroll
        for (int r = 0; r < 4; ++r) {
            hN[b * 512 + j0 + r] = hnew[r];
            cN[b * 512 + j0 + r] = cnew[r];
        }
    }
}

// ---------------------------------------------------------------------------
extern "C" void kernel_launch(void* const* d_in, const int* in_sizes, int n_in,
                              void* d_out, int out_size, void* d_ws, size_t ws_size,
                              hipStream_t stream) {
    const float* x    = (const float*)d_in[0];
    const float* done = (const float*)d_in[1];
    const float* h0   = (const float*)d_in[2];
    const float* c0   = (const float*)d_in[3];
    const float* c1w  = (const float*)d_in[4];
    const float* c1b  = (const float*)d_in[5];
    const float* c2w  = (const float*)d_in[6];
    const float* c2b  = (const float*)d_in[7];
    const float* c3w  = (const float*)d_in[8];
    const float* c3b  = (const float*)d_in[9];
    const float* fc1w = (const float*)d_in[10];
    const float* fc1b = (const float*)d_in[11];
    const float* fc2w = (const float*)d_in[12];
    const float* fc2b = (const float*)d_in[13];
    const float* wih  = (const float*)d_in[14];
    const float* whh  = (const float*)d_in[15];
    const float* bih  = (const float*)d_in[16];
    const float* bhh  = (const float*)d_in[17];
    const float* dfw  = (const float*)d_in[18];
    const float* dfb  = (const float*)d_in[19];
    const float* dw   = (const float*)d_in[20];
    const float* db   = (const float*)d_in[21];
    float* out = (float*)d_out;

    const size_t CONV_ELEMS = 57802752;            // 2048*4*84*84
    char* S = (char*)d_ws;
    unsigned short* c1out  = (unsigned short*)S;   S += CONV_ELEMS * 2;
    unsigned short* c2out  = (unsigned short*)S;   S += CONV_ELEMS * 2;
    unsigned short* c3out  = (unsigned short*)S;   S += CONV_ELEMS * 2;
    unsigned short* fc1w_b = (unsigned short*)S;   S += 28901376;
    unsigned short* fc2w_b = (unsigned short*)S;   S += 524288;
    unsigned short* wih_b  = (unsigned short*)S;   S += 2097152;
    unsigned short* whh_b  = (unsigned short*)S;   S += 2097152;
    unsigned short* dfw_b  = (unsigned short*)S;   S += 131072;
    unsigned short* dw_b   = (unsigned short*)S;   S += 16384;
    unsigned short* hfc1_b = (unsigned short*)S;   S += 2097152;
    unsigned short* hfc2_b = (unsigned short*)S;   S += 2097152;
    float*          gx     = (float*)S;            S += 16777216;
    unsigned short* feat_b = (unsigned short*)S;   S += 2097152;
    unsigned short* dfeat_b= (unsigned short*)S;   S += 524288;
    unsigned short* HA     = (unsigned short*)S;   S += 32768;
    unsigned short* HB     = (unsigned short*)S;   S += 32768;
    float*          cT     = (float*)S;            S += 65536;

    // --- conv stack (LDS-tiled; bf16 intermediates) ---
    dim3 cgrid(2048, 7);
    conv_tile_kernel<5, false, true><<<cgrid, 256, 0, stream>>>(x,     c1w, c1b, c1out);
    conv_tile_kernel<3, true,  true><<<cgrid, 256, 0, stream>>>(c1out, c2w, c2b, c2out);
    conv_tile_kernel<3, true,  true><<<cgrid, 256, 0, stream>>>(c2out, c3w, c3b, c3out);

    // --- weight conversions ---
    auto cvt = [&](const float* s, unsigned short* d, int n) {
        int n4 = n / 4;
        cvt_bf16_kernel<<<(n4 + 255) / 256, 256, 0, stream>>>(s, d, n4);
    };
    cvt(fc1w, fc1w_b, 14450688);
    cvt(fc2w, fc2w_b, 262144);
    cvt(wih,  wih_b,  1048576);
    cvt(whh,  whh_b,  1048576);
    cvt(dfw,  dfw_b,  65536);
    cvt(dw,   dw_b,   8192);

    // --- MLP (bf16 MFMA) ---
    gemm_bf16_kernel<true, false, true><<<dim3(512 / 64, 2048 / 64), 256, 0, stream>>>(
        c3out, fc1w_b, fc1b, nullptr, hfc1_b, 2048, 512, 28224);
    gemm_bf16_kernel<true, false, true><<<dim3(512 / 64, 2048 / 64), 256, 0, stream>>>(
        hfc1_b, fc2w_b, fc2b, nullptr, hfc2_b, 2048, 512, 512);

    // --- x-part of LSTM gates ---
    gemm_bf16_kernel<false, true, false><<<dim3(2048 / 64, 2048 / 64), 256, 0, stream>>>(
        hfc2_b, wih_b, bih, bhh, gx, 2048, 2048, 512);

    // --- LSTM scan ---
    lstm_init_kernel<<<dim3(64), 256, 0, stream>>>(h0, c0, HA, cT);
    unsigned short* hin = HA;
    unsigned short* hout = HB;
    for (int t = 0; t < 64; ++t) {
        float* hNp = (t == 63) ? (out + 131072) : nullptr;
        float* cNp = (t == 63) ? (out + 131072 + 16384) : nullptr;
        lstm_step_kernel<<<dim3(64), dim3(64), 0, stream>>>(
            whh_b, hin, hout, cT, gx, done, feat_b, hNp, cNp, t);
        unsigned short* tmp = hin; hin = hout; hout = tmp;
    }

    // --- discriminator head ---
    gemm_bf16_kernel<true, false, true><<<dim3(128 / 64, 2048 / 64), 256, 0, stream>>>(
        feat_b, dfw_b, dfb, nullptr, dfeat_b, 2048, 128, 512);
    gemm_bf16_kernel<false, false, false><<<dim3(64 / 64, 2048 / 64), 256, 0, stream>>>(
        dfeat_b, dw_b, db, nullptr, out, 2048, 64, 128);
}

// Round 4
// 1311.384 us; speedup vs baseline: 4.1528x; 1.3742x over previous
//
#include <hip/hip_runtime.h>
#include <math.h>

#define SLOPE 0.01f

typedef __attribute__((ext_vector_type(8))) short bf16x8;
typedef __attribute__((ext_vector_type(4))) float f32x4;
typedef unsigned short ushort_t;

__device__ __forceinline__ float lrelu(float x) {
    return x > 0.f ? x : SLOPE * x;
}

__device__ __forceinline__ unsigned short f2bf(float f) {
    unsigned int u = __float_as_uint(f);
    u += 0x7fffu + ((u >> 16) & 1u);
    return (unsigned short)(u >> 16);
}

__device__ __forceinline__ float bf2f(unsigned short u) {
    return __uint_as_float((unsigned int)u << 16);
}

// ---------------------------------------------------------------------------
// f32 -> bf16 conversion, 4 elems/thread
// ---------------------------------------------------------------------------
__global__ void cvt_bf16_kernel(const float* __restrict__ src,
                                unsigned short* __restrict__ dst, int n4) {
    int i = blockIdx.x * blockDim.x + threadIdx.x;
    if (i >= n4) return;
    float4 v = ((const float4*)src)[i];
    uint2 o;
    o.x = (unsigned)f2bf(v.x) | ((unsigned)f2bf(v.y) << 16);
    o.y = (unsigned)f2bf(v.z) | ((unsigned)f2bf(v.w) << 16);
    ((uint2*)dst)[i] = o;
}

// ---------------------------------------------------------------------------
// LDS-tiled conv 4->4, SAME, kernel K, fused bias+LeakyReLU. (unchanged R3)
// ---------------------------------------------------------------------------
template<int K, bool INBF, bool OUTBF>
__global__ __launch_bounds__(256) void conv_tile_kernel(
        const void* __restrict__ in_v,
        const float* __restrict__ w,
        const float* __restrict__ b,
        void* __restrict__ out_v) {
    constexpr int HALO = K / 2;
    constexpr int TILE_H = 12;
    constexpr int SH = TILE_H + 2 * HALO;
    constexpr int SW = 88;
    __shared__ float smem[4][SH][SW];
    __shared__ float wle[4][K][4][K + 1];
    __shared__ float bs[4];

    int tid = threadIdx.x;
    int n = blockIdx.x;
    int row0 = blockIdx.y * TILE_H;
    const size_t imgOff = (size_t)n * (4 * 84 * 84);

    for (int i = tid; i < 16 * K * K; i += 256) {
        int kw = i % K; int t2 = i / K;
        int kh = t2 % K; int t3 = t2 / K;
        int ci = t3 & 3;  int co = t3 >> 2;
        wle[ci][kh][co][kw] = w[i];
    }
    if (tid < 4) bs[tid] = b[tid];

    for (int i = tid; i < 4 * SH * SW; i += 256) {
        int c = i % SW; int t2 = i / SW;
        int r = t2 % SH; int ci = t2 / SH;
        int ih = row0 + r - HALO;
        int iw = c - HALO;
        float v = 0.f;
        if ((unsigned)ih < 84u && (unsigned)iw < 84u) {
            size_t off = imgOff + ((size_t)ci * 84 + ih) * 84 + iw;
            v = INBF ? bf2f(((const ushort_t*)in_v)[off])
                     : ((const float*)in_v)[off];
        }
        smem[ci][r][c] = v;
    }
    __syncthreads();

    if (tid >= 252) return;
    int r  = tid / 21;
    int w0 = (tid % 21) * 4;

    float acc[4][4];
    #pragma unroll
    for (int co = 0; co < 4; ++co)
        #pragma unroll
        for (int dw = 0; dw < 4; ++dw) acc[co][dw] = bs[co];

    #pragma unroll
    for (int ci = 0; ci < 4; ++ci) {
        #pragma unroll
        for (int kh = 0; kh < K; ++kh) {
            float vals[K + 3];
            float4 v0 = *(const float4*)&smem[ci][r + kh][w0];
            vals[0] = v0.x; vals[1] = v0.y; vals[2] = v0.z; vals[3] = v0.w;
            if (K == 5) {
                float4 v1 = *(const float4*)&smem[ci][r + kh][w0 + 4];
                vals[4] = v1.x; vals[5] = v1.y; vals[6] = v1.z; vals[7] = v1.w;
            } else {
                float2 v1 = *(const float2*)&smem[ci][r + kh][w0 + 4];
                vals[4] = v1.x; vals[5] = v1.y;
            }
            #pragma unroll
            for (int co = 0; co < 4; ++co) {
                #pragma unroll
                for (int kw = 0; kw < K; ++kw) {
                    float wv = wle[ci][kh][co][kw];
                    #pragma unroll
                    for (int dw = 0; dw < 4; ++dw)
                        acc[co][dw] += vals[kw + dw] * wv;
                }
            }
        }
    }

    int oh = row0 + r;
    #pragma unroll
    for (int co = 0; co < 4; ++co) {
        size_t off = imgOff + ((size_t)co * 84 + oh) * 84 + w0;
        float o0 = lrelu(acc[co][0]);
        float o1 = lrelu(acc[co][1]);
        float o2 = lrelu(acc[co][2]);
        float o3 = lrelu(acc[co][3]);
        if (OUTBF) {
            uint2 p;
            p.x = (unsigned)f2bf(o0) | ((unsigned)f2bf(o1) << 16);
            p.y = (unsigned)f2bf(o2) | ((unsigned)f2bf(o3) << 16);
            *(uint2*)((ushort_t*)out_v + off) = p;
        } else {
            *(float4*)((float*)out_v + off) = make_float4(o0, o1, o2, o3);
        }
    }
}

// ---------------------------------------------------------------------------
// bf16 MFMA GEMM (NT) with epilogue (fc2, gx, heads). (unchanged R3)
// ---------------------------------------------------------------------------
template<bool DO_LRELU, bool BIAS2, bool OUTBF>
__global__ void gemm_bf16_kernel(const unsigned short* __restrict__ A,
                                 const unsigned short* __restrict__ B,
                                 const float* __restrict__ bias,
                                 const float* __restrict__ bias2,
                                 void* __restrict__ Cout,
                                 int M, int N, int K) {
    __shared__ unsigned short As[64][40];
    __shared__ unsigned short Bs[64][40];
    int tid = threadIdx.x;
    int rowBase = blockIdx.y * 64;
    int colBase = blockIdx.x * 64;

    int wave = tid >> 6;
    int l    = tid & 63;
    int wr = wave >> 1, wc = wave & 1;
    int lane16 = l & 15;
    int kb = (l >> 4) * 8;

    int sr = tid >> 2;
    int sk = (tid & 3) << 3;
    const unsigned short* Ap = A + (size_t)(rowBase + sr) * K + sk;
    const unsigned short* Bp = B + (size_t)(colBase + sr) * K + sk;

    f32x4 acc[2][2] = {};

    for (int k0 = 0; k0 < K; k0 += 32) {
        float4 av = *(const float4*)(Ap + k0);
        float4 bv = *(const float4*)(Bp + k0);
        __syncthreads();
        *(float4*)(&As[sr][sk]) = av;
        *(float4*)(&Bs[sr][sk]) = bv;
        __syncthreads();
        bf16x8 a0 = *(const bf16x8*)(&As[wr * 32 + lane16][kb]);
        bf16x8 a1 = *(const bf16x8*)(&As[wr * 32 + 16 + lane16][kb]);
        bf16x8 b0 = *(const bf16x8*)(&Bs[wc * 32 + lane16][kb]);
        bf16x8 b1 = *(const bf16x8*)(&Bs[wc * 32 + 16 + lane16][kb]);
        acc[0][0] = __builtin_amdgcn_mfma_f32_16x16x32_bf16(a0, b0, acc[0][0], 0, 0, 0);
        acc[0][1] = __builtin_amdgcn_mfma_f32_16x16x32_bf16(a0, b1, acc[0][1], 0, 0, 0);
        acc[1][0] = __builtin_amdgcn_mfma_f32_16x16x32_bf16(a1, b0, acc[1][0], 0, 0, 0);
        acc[1][1] = __builtin_amdgcn_mfma_f32_16x16x32_bf16(a1, b1, acc[1][1], 0, 0, 0);
    }

    int crow0 = rowBase + wr * 32 + (l >> 4) * 4;
    int ccol0 = colBase + wc * 32 + lane16;
    float bsv[2];
    #pragma unroll
    for (int j = 0; j < 2; ++j) {
        bsv[j] = bias[ccol0 + j * 16];
        if (BIAS2) bsv[j] += bias2[ccol0 + j * 16];
    }
    #pragma unroll
    for (int i = 0; i < 2; ++i) {
        #pragma unroll
        for (int r = 0; r < 4; ++r) {
            int row = crow0 + i * 16 + r;
            #pragma unroll
            for (int j = 0; j < 2; ++j) {
                float v = acc[i][j][r] + bsv[j];
                if (DO_LRELU) v = lrelu(v);
                size_t off = (size_t)row * N + ccol0 + j * 16;
                if (OUTBF) ((unsigned short*)Cout)[off] = f2bf(v);
                else       ((float*)Cout)[off] = v;
            }
        }
    }
}

// ---------------------------------------------------------------------------
// Split-K bf16 MFMA GEMM: writes f32 partials (no bias/act).
// blockIdx.z = split s; K-chunk = kChunk (multiple of 32).
// ---------------------------------------------------------------------------
__global__ void gemm_bf16_splitk_kernel(const unsigned short* __restrict__ A,
                                        const unsigned short* __restrict__ B,
                                        float* __restrict__ part,
                                        int M, int N, int K, int kChunk) {
    __shared__ unsigned short As[64][40];
    __shared__ unsigned short Bs[64][40];
    int tid = threadIdx.x;
    int rowBase = blockIdx.y * 64;
    int colBase = blockIdx.x * 64;
    int s = blockIdx.z;
    int kStart = s * kChunk;
    int kEnd = kStart + kChunk;

    int wave = tid >> 6;
    int l    = tid & 63;
    int wr = wave >> 1, wc = wave & 1;
    int lane16 = l & 15;
    int kb = (l >> 4) * 8;

    int sr = tid >> 2;
    int sk = (tid & 3) << 3;
    const unsigned short* Ap = A + (size_t)(rowBase + sr) * K + sk;
    const unsigned short* Bp = B + (size_t)(colBase + sr) * K + sk;

    f32x4 acc[2][2] = {};

    for (int k0 = kStart; k0 < kEnd; k0 += 32) {
        float4 av = *(const float4*)(Ap + k0);
        float4 bv = *(const float4*)(Bp + k0);
        __syncthreads();
        *(float4*)(&As[sr][sk]) = av;
        *(float4*)(&Bs[sr][sk]) = bv;
        __syncthreads();
        bf16x8 a0 = *(const bf16x8*)(&As[wr * 32 + lane16][kb]);
        bf16x8 a1 = *(const bf16x8*)(&As[wr * 32 + 16 + lane16][kb]);
        bf16x8 b0 = *(const bf16x8*)(&Bs[wc * 32 + lane16][kb]);
        bf16x8 b1 = *(const bf16x8*)(&Bs[wc * 32 + 16 + lane16][kb]);
        acc[0][0] = __builtin_amdgcn_mfma_f32_16x16x32_bf16(a0, b0, acc[0][0], 0, 0, 0);
        acc[0][1] = __builtin_amdgcn_mfma_f32_16x16x32_bf16(a0, b1, acc[0][1], 0, 0, 0);
        acc[1][0] = __builtin_amdgcn_mfma_f32_16x16x32_bf16(a1, b0, acc[1][0], 0, 0, 0);
        acc[1][1] = __builtin_amdgcn_mfma_f32_16x16x32_bf16(a1, b1, acc[1][1], 0, 0, 0);
    }

    float* Cp = part + (size_t)s * M * N;
    int crow0 = rowBase + wr * 32 + (l >> 4) * 4;
    int ccol0 = colBase + wc * 32 + lane16;
    #pragma unroll
    for (int i = 0; i < 2; ++i)
        #pragma unroll
        for (int r = 0; r < 4; ++r) {
            int row = crow0 + i * 16 + r;
            #pragma unroll
            for (int j = 0; j < 2; ++j)
                Cp[(size_t)row * N + ccol0 + j * 16] = acc[i][j][r];
        }
}

// ---------------------------------------------------------------------------
// Split-K reduce: out_bf16 = lrelu(sum_s part[s] + bias). Vec4.
// ---------------------------------------------------------------------------
template<int S>
__global__ void splitk_reduce_kernel(const float* __restrict__ part,
                                     const float* __restrict__ bias,
                                     unsigned short* __restrict__ out,
                                     int MN, int N) {
    int i4 = blockIdx.x * blockDim.x + threadIdx.x;
    if (i4 * 4 >= MN) return;
    float4 acc = ((const float4*)part)[i4];
    #pragma unroll
    for (int s = 1; s < S; ++s) {
        float4 p = ((const float4*)(part + (size_t)s * MN))[i4];
        acc.x += p.x; acc.y += p.y; acc.z += p.z; acc.w += p.w;
    }
    int col4 = i4 % (N / 4);
    float4 bv = ((const float4*)bias)[col4];
    float o0 = lrelu(acc.x + bv.x);
    float o1 = lrelu(acc.y + bv.y);
    float o2 = lrelu(acc.z + bv.z);
    float o3 = lrelu(acc.w + bv.w);
    uint2 p;
    p.x = (unsigned)f2bf(o0) | ((unsigned)f2bf(o1) << 16);
    p.y = (unsigned)f2bf(o2) | ((unsigned)f2bf(o3) << 16);
    ((uint2*)out)[i4] = p;
}

// ---------------------------------------------------------------------------
// LSTM init: HA (bf16) from h0; zero barrier words.
// ---------------------------------------------------------------------------
__global__ void lstm_init_kernel(const float* __restrict__ h0,
                                 unsigned short* __restrict__ HA,
                                 int* __restrict__ bar) {
    int i = blockIdx.x * blockDim.x + threadIdx.x;
    if (i < 16384) HA[i] = f2bf(h0[i]);
    if (i < 2) bar[i] = 0;
}

// ---------------------------------------------------------------------------
// Persistent LSTM scan: ONE launch, 64 blocks x 256 threads (4 waves = 4
// gates). Software grid barrier between steps (agent-scope atomics; counters
// zeroed by lstm_init each call). feat doubles as h-history: step t reads
// feat[t-1] (t=0 reads HA). c lives in a register per (j,b)-owning thread.
// ---------------------------------------------------------------------------
__global__ __launch_bounds__(256) void lstm_scan_kernel(
        const unsigned short* __restrict__ whh_b,   // [4*512][512] bf16
        const unsigned short* __restrict__ HA,      // [32][512] bf16
        const float* __restrict__ c0,               // [32][512] f32
        const float* __restrict__ gx,               // [2048][2048] f32
        const float* __restrict__ done,             // [2048] f32
        unsigned short* __restrict__ feat,          // [2048][512] bf16
        float* __restrict__ hN, float* __restrict__ cN,
        int* __restrict__ bar) {
    __shared__ float mds[2048];
    __shared__ float Gs[4][16][17];

    int tid = threadIdx.x;
    int jt = blockIdx.x >> 1;
    int bt = blockIdx.x & 1;

    for (int i = tid; i < 2048; i += 256) mds[i] = 1.0f - done[i];

    // MFMA-phase identity (wave g computes gate g)
    int g = tid >> 6;
    int l = tid & 63;
    int lane16 = l & 15;
    int khi = l >> 4;
    const unsigned short* Wp =
        whh_b + ((size_t)g * 512 + jt * 16 + lane16) * 512 + khi * 8;
    int hoff = (bt * 16 + lane16) * 512 + khi * 8;

    // pointwise-phase identity (thread owns (j,b))
    int jloc = tid & 15;
    int bloc = tid >> 4;
    int j = jt * 16 + jloc;
    int b = bt * 16 + bloc;
    float c_reg = c0[b * 512 + j];

    int* bar_ctr = bar;
    int* bar_rel = bar + 1;

    __syncthreads();

    for (int t = 0; t < 64; ++t) {
        const unsigned short* Hp =
            (t == 0 ? HA : feat + (size_t)(t - 1) * 16384) + hoff;
        f32x4 acc = {};
        #pragma unroll
        for (int k0 = 0; k0 < 512; k0 += 32) {
            bf16x8 wb = *(const bf16x8*)(Wp + k0);
            bf16x8 hb = *(const bf16x8*)(Hp + k0);
            acc = __builtin_amdgcn_mfma_f32_16x16x32_bf16(wb, hb, acc, 0, 0, 0);
        }
        #pragma unroll
        for (int r = 0; r < 4; ++r) Gs[g][khi * 4 + r][lane16] = acc[r];
        __syncthreads();

        // pointwise update
        int row = t * 32 + b;
        const float* gp = gx + (size_t)row * 2048 + j;
        float m = mds[row];
        float ai = gp[0]    + m * Gs[0][jloc][bloc];
        float af = gp[512]  + m * Gs[1][jloc][bloc];
        float ag = gp[1024] + m * Gs[2][jloc][bloc];
        float ao = gp[1536] + m * Gs[3][jloc][bloc];
        float cp = c_reg * m;
        float si = 1.f / (1.f + __expf(-ai));
        float sf = 1.f / (1.f + __expf(-af));
        float so = 1.f / (1.f + __expf(-ao));
        c_reg = sf * cp + si * tanhf(ag);
        float hn = so * tanhf(c_reg);
        feat[(size_t)row * 512 + j] = f2bf(hn);
        if (t == 63) {
            hN[b * 512 + j] = hn;
            cN[b * 512 + j] = c_reg;
        }

        // grid barrier (not needed after the last step)
        if (t < 63) {
            __syncthreads();
            if (tid == 0) {
                __threadfence();
                int target = t + 1;
                int old = __hip_atomic_fetch_add(bar_ctr, 1, __ATOMIC_ACQ_REL,
                                                 __HIP_MEMORY_SCOPE_AGENT);
                if (old == target * 64 - 1) {
                    __hip_atomic_store(bar_rel, target, __ATOMIC_RELEASE,
                                       __HIP_MEMORY_SCOPE_AGENT);
                } else {
                    while (__hip_atomic_load(bar_rel, __ATOMIC_ACQUIRE,
                                             __HIP_MEMORY_SCOPE_AGENT) < target)
                        __builtin_amdgcn_s_sleep(2);
                }
            }
            __syncthreads();
        }
    }
}

// ---------------------------------------------------------------------------
extern "C" void kernel_launch(void* const* d_in, const int* in_sizes, int n_in,
                              void* d_out, int out_size, void* d_ws, size_t ws_size,
                              hipStream_t stream) {
    const float* x    = (const float*)d_in[0];
    const float* done = (const float*)d_in[1];
    const float* h0   = (const float*)d_in[2];
    const float* c0   = (const float*)d_in[3];
    const float* c1w  = (const float*)d_in[4];
    const float* c1b  = (const float*)d_in[5];
    const float* c2w  = (const float*)d_in[6];
    const float* c2b  = (const float*)d_in[7];
    const float* c3w  = (const float*)d_in[8];
    const float* c3b  = (const float*)d_in[9];
    const float* fc1w = (const float*)d_in[10];
    const float* fc1b = (const float*)d_in[11];
    const float* fc2w = (const float*)d_in[12];
    const float* fc2b = (const float*)d_in[13];
    const float* wih  = (const float*)d_in[14];
    const float* whh  = (const float*)d_in[15];
    const float* bih  = (const float*)d_in[16];
    const float* bhh  = (const float*)d_in[17];
    const float* dfw  = (const float*)d_in[18];
    const float* dfb  = (const float*)d_in[19];
    const float* dw   = (const float*)d_in[20];
    const float* db   = (const float*)d_in[21];
    float* out = (float*)d_out;

    const size_t CONV_ELEMS = 57802752;            // 2048*4*84*84
    char* S = (char*)d_ws;
    unsigned short* c1out  = (unsigned short*)S;   S += CONV_ELEMS * 2;
    unsigned short* c2out  = (unsigned short*)S;   S += CONV_ELEMS * 2;
    unsigned short* c3out  = (unsigned short*)S;   S += CONV_ELEMS * 2;
    unsigned short* fc1w_b = (unsigned short*)S;   S += 28901376;
    unsigned short* fc2w_b = (unsigned short*)S;   S += 524288;
    unsigned short* wih_b  = (unsigned short*)S;   S += 2097152;
    unsigned short* whh_b  = (unsigned short*)S;   S += 2097152;
    unsigned short* dfw_b  = (unsigned short*)S;   S += 131072;
    unsigned short* dw_b   = (unsigned short*)S;   S += 16384;
    unsigned short* hfc1_b = (unsigned short*)S;   S += 2097152;
    unsigned short* hfc2_b = (unsigned short*)S;   S += 2097152;
    float*          gx     = (float*)S;            S += 16777216;
    unsigned short* feat_b = (unsigned short*)S;   S += 2097152;
    unsigned short* dfeat_b= (unsigned short*)S;   S += 524288;
    unsigned short* HA     = (unsigned short*)S;   S += 32768;
    float*          part   = (float*)S;            S += 25165824;  // 6x[2048][512] f32
    int*            bar    = (int*)S;              S += 256;

    // --- conv stack ---
    dim3 cgrid(2048, 7);
    conv_tile_kernel<5, false, true><<<cgrid, 256, 0, stream>>>(x,     c1w, c1b, c1out);
    conv_tile_kernel<3, true,  true><<<cgrid, 256, 0, stream>>>(c1out, c2w, c2b, c2out);
    conv_tile_kernel<3, true,  true><<<cgrid, 256, 0, stream>>>(c2out, c3w, c3b, c3out);

    // --- weight conversions ---
    auto cvt = [&](const float* s, unsigned short* d, int n) {
        int n4 = n / 4;
        cvt_bf16_kernel<<<(n4 + 255) / 256, 256, 0, stream>>>(s, d, n4);
    };
    cvt(fc1w, fc1w_b, 14450688);
    cvt(fc2w, fc2w_b, 262144);
    cvt(wih,  wih_b,  1048576);
    cvt(whh,  whh_b,  1048576);
    cvt(dfw,  dfw_b,  65536);
    cvt(dw,   dw_b,   8192);

    // --- fc1: split-K x6 (K = 28224 = 6*4704), then reduce+bias+lrelu ---
    gemm_bf16_splitk_kernel<<<dim3(8, 32, 6), 256, 0, stream>>>(
        c3out, fc1w_b, part, 2048, 512, 28224, 4704);
    splitk_reduce_kernel<6><<<dim3(1024), 256, 0, stream>>>(
        part, fc1b, hfc1_b, 1048576, 512);

    // --- fc2 ---
    gemm_bf16_kernel<true, false, true><<<dim3(8, 32), 256, 0, stream>>>(
        hfc1_b, fc2w_b, fc2b, nullptr, hfc2_b, 2048, 512, 512);

    // --- x-part of LSTM gates ---
    gemm_bf16_kernel<false, true, false><<<dim3(32, 32), 256, 0, stream>>>(
        hfc2_b, wih_b, bih, bhh, gx, 2048, 2048, 512);

    // --- LSTM scan (single persistent launch) ---
    lstm_init_kernel<<<dim3(64), 256, 0, stream>>>(h0, HA, bar);
    lstm_scan_kernel<<<dim3(64), 256, 0, stream>>>(
        whh_b, HA, c0, gx, done, feat_b,
        out + 131072, out + 131072 + 16384, bar);

    // --- discriminator head ---
    gemm_bf16_kernel<true, false, true><<<dim3(2, 32), 256, 0, stream>>>(
        feat_b, dfw_b, dfb, nullptr, dfeat_b, 2048, 128, 512);
    gemm_bf16_kernel<false, false, false><<<dim3(1, 32), 256, 0, stream>>>(
        dfeat_b, dw_b, db, nullptr, out, 2048, 64, 128);
}

// Round 6
// 1225.406 us; speedup vs baseline: 4.4441x; 1.0702x over previous
//
#include <hip/hip_runtime.h>
#include <math.h>

#define SLOPE 0.01f

typedef __attribute__((ext_vector_type(8))) short bf16x8;
typedef __attribute__((ext_vector_type(4))) float f32x4;
typedef unsigned short ushort_t;

__device__ __forceinline__ float lrelu(float x) {
    return x > 0.f ? x : SLOPE * x;
}

__device__ __forceinline__ unsigned short f2bf(float f) {
    unsigned int u = __float_as_uint(f);
    u += 0x7fffu + ((u >> 16) & 1u);
    return (unsigned short)(u >> 16);
}

__device__ __forceinline__ float bf2f(unsigned short u) {
    return __uint_as_float((unsigned int)u << 16);
}

// ---------------------------------------------------------------------------
// f32 -> bf16 conversion, 4 elems/thread
// ---------------------------------------------------------------------------
__global__ void cvt_bf16_kernel(const float* __restrict__ src,
                                unsigned short* __restrict__ dst, int n4) {
    int i = blockIdx.x * blockDim.x + threadIdx.x;
    if (i >= n4) return;
    float4 v = ((const float4*)src)[i];
    uint2 o;
    o.x = (unsigned)f2bf(v.x) | ((unsigned)f2bf(v.y) << 16);
    o.y = (unsigned)f2bf(v.z) | ((unsigned)f2bf(v.w) << 16);
    ((uint2*)dst)[i] = o;
}

// ---------------------------------------------------------------------------
// LDS-tiled conv 4->4, SAME, kernel K, fused bias+LeakyReLU. (unchanged)
// ---------------------------------------------------------------------------
template<int K, bool INBF, bool OUTBF>
__global__ __launch_bounds__(256) void conv_tile_kernel(
        const void* __restrict__ in_v,
        const float* __restrict__ w,
        const float* __restrict__ b,
        void* __restrict__ out_v) {
    constexpr int HALO = K / 2;
    constexpr int TILE_H = 12;
    constexpr int SH = TILE_H + 2 * HALO;
    constexpr int SW = 88;
    __shared__ float smem[4][SH][SW];
    __shared__ float wle[4][K][4][K + 1];
    __shared__ float bs[4];

    int tid = threadIdx.x;
    int n = blockIdx.x;
    int row0 = blockIdx.y * TILE_H;
    const size_t imgOff = (size_t)n * (4 * 84 * 84);

    for (int i = tid; i < 16 * K * K; i += 256) {
        int kw = i % K; int t2 = i / K;
        int kh = t2 % K; int t3 = t2 / K;
        int ci = t3 & 3;  int co = t3 >> 2;
        wle[ci][kh][co][kw] = w[i];
    }
    if (tid < 4) bs[tid] = b[tid];

    for (int i = tid; i < 4 * SH * SW; i += 256) {
        int c = i % SW; int t2 = i / SW;
        int r = t2 % SH; int ci = t2 / SH;
        int ih = row0 + r - HALO;
        int iw = c - HALO;
        float v = 0.f;
        if ((unsigned)ih < 84u && (unsigned)iw < 84u) {
            size_t off = imgOff + ((size_t)ci * 84 + ih) * 84 + iw;
            v = INBF ? bf2f(((const ushort_t*)in_v)[off])
                     : ((const float*)in_v)[off];
        }
        smem[ci][r][c] = v;
    }
    __syncthreads();

    if (tid >= 252) return;
    int r  = tid / 21;
    int w0 = (tid % 21) * 4;

    float acc[4][4];
    #pragma unroll
    for (int co = 0; co < 4; ++co)
        #pragma unroll
        for (int dw = 0; dw < 4; ++dw) acc[co][dw] = bs[co];

    #pragma unroll
    for (int ci = 0; ci < 4; ++ci) {
        #pragma unroll
        for (int kh = 0; kh < K; ++kh) {
            float vals[K + 3];
            float4 v0 = *(const float4*)&smem[ci][r + kh][w0];
            vals[0] = v0.x; vals[1] = v0.y; vals[2] = v0.z; vals[3] = v0.w;
            if (K == 5) {
                float4 v1 = *(const float4*)&smem[ci][r + kh][w0 + 4];
                vals[4] = v1.x; vals[5] = v1.y; vals[6] = v1.z; vals[7] = v1.w;
            } else {
                float2 v1 = *(const float2*)&smem[ci][r + kh][w0 + 4];
                vals[4] = v1.x; vals[5] = v1.y;
            }
            #pragma unroll
            for (int co = 0; co < 4; ++co) {
                #pragma unroll
                for (int kw = 0; kw < K; ++kw) {
                    float wv = wle[ci][kh][co][kw];
                    #pragma unroll
                    for (int dw = 0; dw < 4; ++dw)
                        acc[co][dw] += vals[kw + dw] * wv;
                }
            }
        }
    }

    int oh = row0 + r;
    #pragma unroll
    for (int co = 0; co < 4; ++co) {
        size_t off = imgOff + ((size_t)co * 84 + oh) * 84 + w0;
        float o0 = lrelu(acc[co][0]);
        float o1 = lrelu(acc[co][1]);
        float o2 = lrelu(acc[co][2]);
        float o3 = lrelu(acc[co][3]);
        if (OUTBF) {
            uint2 p;
            p.x = (unsigned)f2bf(o0) | ((unsigned)f2bf(o1) << 16);
            p.y = (unsigned)f2bf(o2) | ((unsigned)f2bf(o3) << 16);
            *(uint2*)((ushort_t*)out_v + off) = p;
        } else {
            *(float4*)((float*)out_v + off) = make_float4(o0, o1, o2, o3);
        }
    }
}

// ---------------------------------------------------------------------------
// bf16 MFMA GEMM (NT) with epilogue (fc2, gx, heads). (unchanged)
// ---------------------------------------------------------------------------
template<bool DO_LRELU, bool BIAS2, bool OUTBF>
__global__ void gemm_bf16_kernel(const unsigned short* __restrict__ A,
                                 const unsigned short* __restrict__ B,
                                 const float* __restrict__ bias,
                                 const float* __restrict__ bias2,
                                 void* __restrict__ Cout,
                                 int M, int N, int K) {
    __shared__ unsigned short As[64][40];
    __shared__ unsigned short Bs[64][40];
    int tid = threadIdx.x;
    int rowBase = blockIdx.y * 64;
    int colBase = blockIdx.x * 64;

    int wave = tid >> 6;
    int l    = tid & 63;
    int wr = wave >> 1, wc = wave & 1;
    int lane16 = l & 15;
    int kb = (l >> 4) * 8;

    int sr = tid >> 2;
    int sk = (tid & 3) << 3;
    const unsigned short* Ap = A + (size_t)(rowBase + sr) * K + sk;
    const unsigned short* Bp = B + (size_t)(colBase + sr) * K + sk;

    f32x4 acc[2][2] = {};

    for (int k0 = 0; k0 < K; k0 += 32) {
        float4 av = *(const float4*)(Ap + k0);
        float4 bv = *(const float4*)(Bp + k0);
        __syncthreads();
        *(float4*)(&As[sr][sk]) = av;
        *(float4*)(&Bs[sr][sk]) = bv;
        __syncthreads();
        bf16x8 a0 = *(const bf16x8*)(&As[wr * 32 + lane16][kb]);
        bf16x8 a1 = *(const bf16x8*)(&As[wr * 32 + 16 + lane16][kb]);
        bf16x8 b0 = *(const bf16x8*)(&Bs[wc * 32 + lane16][kb]);
        bf16x8 b1 = *(const bf16x8*)(&Bs[wc * 32 + 16 + lane16][kb]);
        acc[0][0] = __builtin_amdgcn_mfma_f32_16x16x32_bf16(a0, b0, acc[0][0], 0, 0, 0);
        acc[0][1] = __builtin_amdgcn_mfma_f32_16x16x32_bf16(a0, b1, acc[0][1], 0, 0, 0);
        acc[1][0] = __builtin_amdgcn_mfma_f32_16x16x32_bf16(a1, b0, acc[1][0], 0, 0, 0);
        acc[1][1] = __builtin_amdgcn_mfma_f32_16x16x32_bf16(a1, b1, acc[1][1], 0, 0, 0);
    }

    int crow0 = rowBase + wr * 32 + (l >> 4) * 4;
    int ccol0 = colBase + wc * 32 + lane16;
    float bsv[2];
    #pragma unroll
    for (int j = 0; j < 2; ++j) {
        bsv[j] = bias[ccol0 + j * 16];
        if (BIAS2) bsv[j] += bias2[ccol0 + j * 16];
    }
    #pragma unroll
    for (int i = 0; i < 2; ++i) {
        #pragma unroll
        for (int r = 0; r < 4; ++r) {
            int row = crow0 + i * 16 + r;
            #pragma unroll
            for (int j = 0; j < 2; ++j) {
                float v = acc[i][j][r] + bsv[j];
                if (DO_LRELU) v = lrelu(v);
                size_t off = (size_t)row * N + ccol0 + j * 16;
                if (OUTBF) ((unsigned short*)Cout)[off] = f2bf(v);
                else       ((float*)Cout)[off] = v;
            }
        }
    }
}

// ---------------------------------------------------------------------------
// Split-K bf16 MFMA GEMM: writes f32 partials. (unchanged)
// ---------------------------------------------------------------------------
__global__ void gemm_bf16_splitk_kernel(const unsigned short* __restrict__ A,
                                        const unsigned short* __restrict__ B,
                                        float* __restrict__ part,
                                        int M, int N, int K, int kChunk) {
    __shared__ unsigned short As[64][40];
    __shared__ unsigned short Bs[64][40];
    int tid = threadIdx.x;
    int rowBase = blockIdx.y * 64;
    int colBase = blockIdx.x * 64;
    int s = blockIdx.z;
    int kStart = s * kChunk;
    int kEnd = kStart + kChunk;

    int wave = tid >> 6;
    int l    = tid & 63;
    int wr = wave >> 1, wc = wave & 1;
    int lane16 = l & 15;
    int kb = (l >> 4) * 8;

    int sr = tid >> 2;
    int sk = (tid & 3) << 3;
    const unsigned short* Ap = A + (size_t)(rowBase + sr) * K + sk;
    const unsigned short* Bp = B + (size_t)(colBase + sr) * K + sk;

    f32x4 acc[2][2] = {};

    for (int k0 = kStart; k0 < kEnd; k0 += 32) {
        float4 av = *(const float4*)(Ap + k0);
        float4 bv = *(const float4*)(Bp + k0);
        __syncthreads();
        *(float4*)(&As[sr][sk]) = av;
        *(float4*)(&Bs[sr][sk]) = bv;
        __syncthreads();
        bf16x8 a0 = *(const bf16x8*)(&As[wr * 32 + lane16][kb]);
        bf16x8 a1 = *(const bf16x8*)(&As[wr * 32 + 16 + lane16][kb]);
        bf16x8 b0 = *(const bf16x8*)(&Bs[wc * 32 + lane16][kb]);
        bf16x8 b1 = *(const bf16x8*)(&Bs[wc * 32 + 16 + lane16][kb]);
        acc[0][0] = __builtin_amdgcn_mfma_f32_16x16x32_bf16(a0, b0, acc[0][0], 0, 0, 0);
        acc[0][1] = __builtin_amdgcn_mfma_f32_16x16x32_bf16(a0, b1, acc[0][1], 0, 0, 0);
        acc[1][0] = __builtin_amdgcn_mfma_f32_16x16x32_bf16(a1, b0, acc[1][0], 0, 0, 0);
        acc[1][1] = __builtin_amdgcn_mfma_f32_16x16x32_bf16(a1, b1, acc[1][1], 0, 0, 0);
    }

    float* Cp = part + (size_t)s * M * N;
    int crow0 = rowBase + wr * 32 + (l >> 4) * 4;
    int ccol0 = colBase + wc * 32 + lane16;
    #pragma unroll
    for (int i = 0; i < 2; ++i)
        #pragma unroll
        for (int r = 0; r < 4; ++r) {
            int row = crow0 + i * 16 + r;
            #pragma unroll
            for (int j = 0; j < 2; ++j)
                Cp[(size_t)row * N + ccol0 + j * 16] = acc[i][j][r];
        }
}

// ---------------------------------------------------------------------------
// Split-K reduce. (unchanged)
// ---------------------------------------------------------------------------
template<int S>
__global__ void splitk_reduce_kernel(const float* __restrict__ part,
                                     const float* __restrict__ bias,
                                     unsigned short* __restrict__ out,
                                     int MN, int N) {
    int i4 = blockIdx.x * blockDim.x + threadIdx.x;
    if (i4 * 4 >= MN) return;
    float4 acc = ((const float4*)part)[i4];
    #pragma unroll
    for (int s = 1; s < S; ++s) {
        float4 p = ((const float4*)(part + (size_t)s * MN))[i4];
        acc.x += p.x; acc.y += p.y; acc.z += p.z; acc.w += p.w;
    }
    int col4 = i4 % (N / 4);
    float4 bv = ((const float4*)bias)[col4];
    float o0 = lrelu(acc.x + bv.x);
    float o1 = lrelu(acc.y + bv.y);
    float o2 = lrelu(acc.z + bv.z);
    float o3 = lrelu(acc.w + bv.w);
    uint2 p;
    p.x = (unsigned)f2bf(o0) | ((unsigned)f2bf(o1) << 16);
    p.y = (unsigned)f2bf(o2) | ((unsigned)f2bf(o3) << 16);
    ((uint2*)out)[i4] = p;
}

// ---------------------------------------------------------------------------
// LSTM init: HA (bf16) = h0; zero both barrier words.
// ---------------------------------------------------------------------------
__global__ void lstm_init_kernel(const float* __restrict__ h0,
                                 unsigned short* __restrict__ HA,
                                 int* __restrict__ bar) {
    int i = blockIdx.x * blockDim.x + threadIdx.x;
    if (i < 16384) HA[i] = f2bf(h0[i]);
    if (i < 2) bar[i] = 0;
}

// ---------------------------------------------------------------------------
// Persistent LSTM scan (R4-proven release/acquire barrier), with:
//  - Whh fragment held in 64 VGPRs per wave (loaded once; survives L2 inv)
//  - gx for step t+1 prefetched into regs BEFORE the barrier (read-only input)
//  - H staged via LDS once per block (plain loads after acquire)
// feat doubles as h-history: step t reads feat[t-1] (t=0 reads HA).
// ---------------------------------------------------------------------------
__global__ __launch_bounds__(256) void lstm_scan_kernel(
        const unsigned short* __restrict__ whh_b,   // [4*512][512] bf16
        const unsigned short* __restrict__ HA,      // [32][512] bf16
        const float* __restrict__ c0,               // [32][512] f32
        const float* __restrict__ gx,               // [2048][2048] f32
        const float* __restrict__ done,             // [2048] f32
        unsigned short* __restrict__ feat,          // [2048][512] bf16
        float* __restrict__ hN, float* __restrict__ cN,
        int* __restrict__ bar) {
    __shared__ float mds[2048];
    __shared__ float Gs[4][16][17];
    __shared__ unsigned short Hs[16][520];          // 1040B row stride: 16B-aligned

    int tid = threadIdx.x;
    int jt = blockIdx.x >> 1;
    int bt = blockIdx.x & 1;

    for (int i = tid; i < 2048; i += 256) mds[i] = 1.0f - done[i];

    // MFMA identity (wave g computes gate g); W fragment -> registers (once)
    int g = tid >> 6;
    int l = tid & 63;
    int lane16 = l & 15;
    int khi = l >> 4;
    const unsigned short* Wp =
        whh_b + ((size_t)g * 512 + jt * 16 + lane16) * 512 + khi * 8;
    bf16x8 wreg[16];
    #pragma unroll
    for (int kk = 0; kk < 16; ++kk)
        wreg[kk] = *(const bf16x8*)(Wp + kk * 32);

    // pointwise identity (thread owns (j,b))
    int jloc = tid & 15;
    int bloc = tid >> 4;
    int j = jt * 16 + jloc;
    int b = bt * 16 + bloc;
    float c_reg = c0[b * 512 + j];

    // prefetch gx for t=0
    const float* gp0 = gx + (size_t)b * 2048 + j;
    float gi = gp0[0], gf = gp0[512], gg = gp0[1024], go = gp0[1536];

    int* bar_ctr = bar;
    int* bar_rel = bar + 1;

    __syncthreads();

    for (int t = 0; t < 64; ++t) {
        // --- cooperative load of our 16-batch half of h_{t-1} into LDS ---
        const unsigned short* Hsrc =
            (t == 0 ? HA : feat + (size_t)(t - 1) * 16384) + bt * 8192;
        const float4* src4 = (const float4*)Hsrc;    // 1024 x float4 (16 KB)
        #pragma unroll
        for (int u0 = 0; u0 < 4; ++u0) {
            int u = tid + u0 * 256;
            float4 v = src4[u];
            int brow = u >> 6;                        // 64 float4 per 512-row
            int koff = (u & 63) * 8;
            *(float4*)&Hs[brow][koff] = v;
        }
        __syncthreads();

        // --- gate GEMM: W from regs, H from LDS; 2-way split accumulator ---
        f32x4 acc0 = {}, acc1 = {};
        #pragma unroll
        for (int kk = 0; kk < 16; kk += 2) {
            bf16x8 hb0 = *(const bf16x8*)(&Hs[lane16][khi * 8 + kk * 32]);
            bf16x8 hb1 = *(const bf16x8*)(&Hs[lane16][khi * 8 + kk * 32 + 32]);
            acc0 = __builtin_amdgcn_mfma_f32_16x16x32_bf16(wreg[kk],     hb0, acc0, 0, 0, 0);
            acc1 = __builtin_amdgcn_mfma_f32_16x16x32_bf16(wreg[kk + 1], hb1, acc1, 0, 0, 0);
        }
        f32x4 acc = acc0 + acc1;
        #pragma unroll
        for (int r = 0; r < 4; ++r) Gs[g][khi * 4 + r][lane16] = acc[r];

        // --- prefetch next step's gx into regs (read-only; pre-barrier ok) ---
        float gi_n = 0.f, gf_n = 0.f, gg_n = 0.f, go_n = 0.f;
        if (t < 63) {
            const float* gp = gx + (size_t)((t + 1) * 32 + b) * 2048 + j;
            gi_n = gp[0]; gf_n = gp[512]; gg_n = gp[1024]; go_n = gp[1536];
        }
        __syncthreads();

        // --- pointwise update ---
        int row = t * 32 + b;
        float m = mds[row];
        float ai = gi + m * Gs[0][jloc][bloc];
        float af = gf + m * Gs[1][jloc][bloc];
        float ag = gg + m * Gs[2][jloc][bloc];
        float ao = go + m * Gs[3][jloc][bloc];
        float cp = c_reg * m;
        float si = 1.f / (1.f + __expf(-ai));
        float sf = 1.f / (1.f + __expf(-af));
        float so = 1.f / (1.f + __expf(-ao));
        c_reg = sf * cp + si * tanhf(ag);
        float hn = so * tanhf(c_reg);
        feat[(size_t)row * 512 + j] = f2bf(hn);
        if (t == 63) {
            hN[b * 512 + j] = hn;
            cN[b * 512 + j] = c_reg;
        }
        gi = gi_n; gf = gf_n; gg = gg_n; go = go_n;

        // --- grid barrier (release/acquire; proven R4 semantics) ---
        if (t < 63) {
            __syncthreads();
            if (tid == 0) {
                __threadfence();
                int target = t + 1;
                int old = __hip_atomic_fetch_add(bar_ctr, 1, __ATOMIC_ACQ_REL,
                                                 __HIP_MEMORY_SCOPE_AGENT);
                if (old == target * 64 - 1) {
                    __hip_atomic_store(bar_rel, target, __ATOMIC_RELEASE,
                                       __HIP_MEMORY_SCOPE_AGENT);
                } else {
                    while (__hip_atomic_load(bar_rel, __ATOMIC_ACQUIRE,
                                             __HIP_MEMORY_SCOPE_AGENT) < target)
                        __builtin_amdgcn_s_sleep(2);
                }
            }
            __syncthreads();
        }
    }
}

// ---------------------------------------------------------------------------
extern "C" void kernel_launch(void* const* d_in, const int* in_sizes, int n_in,
                              void* d_out, int out_size, void* d_ws, size_t ws_size,
                              hipStream_t stream) {
    const float* x    = (const float*)d_in[0];
    const float* done = (const float*)d_in[1];
    const float* h0   = (const float*)d_in[2];
    const float* c0   = (const float*)d_in[3];
    const float* c1w  = (const float*)d_in[4];
    const float* c1b  = (const float*)d_in[5];
    const float* c2w  = (const float*)d_in[6];
    const float* c2b  = (const float*)d_in[7];
    const float* c3w  = (const float*)d_in[8];
    const float* c3b  = (const float*)d_in[9];
    const float* fc1w = (const float*)d_in[10];
    const float* fc1b = (const float*)d_in[11];
    const float* fc2w = (const float*)d_in[12];
    const float* fc2b = (const float*)d_in[13];
    const float* wih  = (const float*)d_in[14];
    const float* whh  = (const float*)d_in[15];
    const float* bih  = (const float*)d_in[16];
    const float* bhh  = (const float*)d_in[17];
    const float* dfw  = (const float*)d_in[18];
    const float* dfb  = (const float*)d_in[19];
    const float* dw   = (const float*)d_in[20];
    const float* db   = (const float*)d_in[21];
    float* out = (float*)d_out;

    const size_t CONV_ELEMS = 57802752;            // 2048*4*84*84
    char* S = (char*)d_ws;
    unsigned short* c1out  = (unsigned short*)S;   S += CONV_ELEMS * 2;
    unsigned short* c2out  = (unsigned short*)S;   S += CONV_ELEMS * 2;
    unsigned short* c3out  = (unsigned short*)S;   S += CONV_ELEMS * 2;
    unsigned short* fc1w_b = (unsigned short*)S;   S += 28901376;
    unsigned short* fc2w_b = (unsigned short*)S;   S += 524288;
    unsigned short* wih_b  = (unsigned short*)S;   S += 2097152;
    unsigned short* whh_b  = (unsigned short*)S;   S += 2097152;
    unsigned short* dfw_b  = (unsigned short*)S;   S += 131072;
    unsigned short* dw_b   = (unsigned short*)S;   S += 16384;
    unsigned short* hfc1_b = (unsigned short*)S;   S += 2097152;
    unsigned short* hfc2_b = (unsigned short*)S;   S += 2097152;
    float*          gx     = (float*)S;            S += 16777216;
    unsigned short* feat_b = (unsigned short*)S;   S += 2097152;
    unsigned short* dfeat_b= (unsigned short*)S;   S += 524288;
    unsigned short* HA     = (unsigned short*)S;   S += 32768;
    float*          part   = (float*)S;            S += 25165824;
    int*            bar    = (int*)S;              S += 256;

    // --- conv stack ---
    dim3 cgrid(2048, 7);
    conv_tile_kernel<5, false, true><<<cgrid, 256, 0, stream>>>(x,     c1w, c1b, c1out);
    conv_tile_kernel<3, true,  true><<<cgrid, 256, 0, stream>>>(c1out, c2w, c2b, c2out);
    conv_tile_kernel<3, true,  true><<<cgrid, 256, 0, stream>>>(c2out, c3w, c3b, c3out);

    // --- weight conversions ---
    auto cvt = [&](const float* s, unsigned short* d, int n) {
        int n4 = n / 4;
        cvt_bf16_kernel<<<(n4 + 255) / 256, 256, 0, stream>>>(s, d, n4);
    };
    cvt(fc1w, fc1w_b, 14450688);
    cvt(fc2w, fc2w_b, 262144);
    cvt(wih,  wih_b,  1048576);
    cvt(whh,  whh_b,  1048576);
    cvt(dfw,  dfw_b,  65536);
    cvt(dw,   dw_b,   8192);

    // --- fc1: split-K x6, then reduce+bias+lrelu ---
    gemm_bf16_splitk_kernel<<<dim3(8, 32, 6), 256, 0, stream>>>(
        c3out, fc1w_b, part, 2048, 512, 28224, 4704);
    splitk_reduce_kernel<6><<<dim3(1024), 256, 0, stream>>>(
        part, fc1b, hfc1_b, 1048576, 512);

    // --- fc2 ---
    gemm_bf16_kernel<true, false, true><<<dim3(8, 32), 256, 0, stream>>>(
        hfc1_b, fc2w_b, fc2b, nullptr, hfc2_b, 2048, 512, 512);

    // --- x-part of LSTM gates ---
    gemm_bf16_kernel<false, true, false><<<dim3(32, 32), 256, 0, stream>>>(
        hfc2_b, wih_b, bih, bhh, gx, 2048, 2048, 512);

    // --- LSTM scan (single persistent launch) ---
    lstm_init_kernel<<<dim3(64), 256, 0, stream>>>(h0, HA, bar);
    lstm_scan_kernel<<<dim3(64), 256, 0, stream>>>(
        whh_b, HA, c0, gx, done, feat_b,
        out + 131072, out + 131072 + 16384, bar);

    // --- discriminator head ---
    gemm_bf16_kernel<true, false, true><<<dim3(2, 32), 256, 0, stream>>>(
        feat_b, dfw_b, dfb, nullptr, dfeat_b, 2048, 128, 512);
    gemm_bf16_kernel<false, false, false><<<dim3(1, 32), 256, 0, stream>>>(
        dfeat_b, dw_b, db, nullptr, out, 2048, 64, 128);
}

// Round 7
// 1111.520 us; speedup vs baseline: 4.8995x; 1.1025x over previous
//
#include <hip/hip_runtime.h>
#include <math.h>

#define SLOPE 0.01f

typedef __attribute__((ext_vector_type(8))) short bf16x8;
typedef __attribute__((ext_vector_type(4))) float f32x4;
typedef unsigned short ushort_t;

__device__ __forceinline__ float lrelu(float x) {
    return x > 0.f ? x : SLOPE * x;
}

__device__ __forceinline__ unsigned short f2bf(float f) {
    unsigned int u = __float_as_uint(f);
    u += 0x7fffu + ((u >> 16) & 1u);
    return (unsigned short)(u >> 16);
}

__device__ __forceinline__ float bf2f(unsigned short u) {
    return __uint_as_float((unsigned int)u << 16);
}

// ---------------------------------------------------------------------------
// f32 -> bf16 conversion, 4 elems/thread
// ---------------------------------------------------------------------------
__global__ void cvt_bf16_kernel(const float* __restrict__ src,
                                unsigned short* __restrict__ dst, int n4) {
    int i = blockIdx.x * blockDim.x + threadIdx.x;
    if (i >= n4) return;
    float4 v = ((const float4*)src)[i];
    uint2 o;
    o.x = (unsigned)f2bf(v.x) | ((unsigned)f2bf(v.y) << 16);
    o.y = (unsigned)f2bf(v.z) | ((unsigned)f2bf(v.w) << 16);
    ((uint2*)dst)[i] = o;
}

// ---------------------------------------------------------------------------
// LDS-tiled conv 4->4, SAME, kernel K, fused bias+LeakyReLU. (unchanged)
// ---------------------------------------------------------------------------
template<int K, bool INBF, bool OUTBF>
__global__ __launch_bounds__(256) void conv_tile_kernel(
        const void* __restrict__ in_v,
        const float* __restrict__ w,
        const float* __restrict__ b,
        void* __restrict__ out_v) {
    constexpr int HALO = K / 2;
    constexpr int TILE_H = 12;
    constexpr int SH = TILE_H + 2 * HALO;
    constexpr int SW = 88;
    __shared__ float smem[4][SH][SW];
    __shared__ float wle[4][K][4][K + 1];
    __shared__ float bs[4];

    int tid = threadIdx.x;
    int n = blockIdx.x;
    int row0 = blockIdx.y * TILE_H;
    const size_t imgOff = (size_t)n * (4 * 84 * 84);

    for (int i = tid; i < 16 * K * K; i += 256) {
        int kw = i % K; int t2 = i / K;
        int kh = t2 % K; int t3 = t2 / K;
        int ci = t3 & 3;  int co = t3 >> 2;
        wle[ci][kh][co][kw] = w[i];
    }
    if (tid < 4) bs[tid] = b[tid];

    for (int i = tid; i < 4 * SH * SW; i += 256) {
        int c = i % SW; int t2 = i / SW;
        int r = t2 % SH; int ci = t2 / SH;
        int ih = row0 + r - HALO;
        int iw = c - HALO;
        float v = 0.f;
        if ((unsigned)ih < 84u && (unsigned)iw < 84u) {
            size_t off = imgOff + ((size_t)ci * 84 + ih) * 84 + iw;
            v = INBF ? bf2f(((const ushort_t*)in_v)[off])
                     : ((const float*)in_v)[off];
        }
        smem[ci][r][c] = v;
    }
    __syncthreads();

    if (tid >= 252) return;
    int r  = tid / 21;
    int w0 = (tid % 21) * 4;

    float acc[4][4];
    #pragma unroll
    for (int co = 0; co < 4; ++co)
        #pragma unroll
        for (int dw = 0; dw < 4; ++dw) acc[co][dw] = bs[co];

    #pragma unroll
    for (int ci = 0; ci < 4; ++ci) {
        #pragma unroll
        for (int kh = 0; kh < K; ++kh) {
            float vals[K + 3];
            float4 v0 = *(const float4*)&smem[ci][r + kh][w0];
            vals[0] = v0.x; vals[1] = v0.y; vals[2] = v0.z; vals[3] = v0.w;
            if (K == 5) {
                float4 v1 = *(const float4*)&smem[ci][r + kh][w0 + 4];
                vals[4] = v1.x; vals[5] = v1.y; vals[6] = v1.z; vals[7] = v1.w;
            } else {
                float2 v1 = *(const float2*)&smem[ci][r + kh][w0 + 4];
                vals[4] = v1.x; vals[5] = v1.y;
            }
            #pragma unroll
            for (int co = 0; co < 4; ++co) {
                #pragma unroll
                for (int kw = 0; kw < K; ++kw) {
                    float wv = wle[ci][kh][co][kw];
                    #pragma unroll
                    for (int dw = 0; dw < 4; ++dw)
                        acc[co][dw] += vals[kw + dw] * wv;
                }
            }
        }
    }

    int oh = row0 + r;
    #pragma unroll
    for (int co = 0; co < 4; ++co) {
        size_t off = imgOff + ((size_t)co * 84 + oh) * 84 + w0;
        float o0 = lrelu(acc[co][0]);
        float o1 = lrelu(acc[co][1]);
        float o2 = lrelu(acc[co][2]);
        float o3 = lrelu(acc[co][3]);
        if (OUTBF) {
            uint2 p;
            p.x = (unsigned)f2bf(o0) | ((unsigned)f2bf(o1) << 16);
            p.y = (unsigned)f2bf(o2) | ((unsigned)f2bf(o3) << 16);
            *(uint2*)((ushort_t*)out_v + off) = p;
        } else {
            *(float4*)((float*)out_v + off) = make_float4(o0, o1, o2, o3);
        }
    }
}

// ---------------------------------------------------------------------------
// bf16 MFMA GEMM (NT) with epilogue (fc2, gx, heads). (unchanged)
// ---------------------------------------------------------------------------
template<bool DO_LRELU, bool BIAS2, bool OUTBF>
__global__ void gemm_bf16_kernel(const unsigned short* __restrict__ A,
                                 const unsigned short* __restrict__ B,
                                 const float* __restrict__ bias,
                                 const float* __restrict__ bias2,
                                 void* __restrict__ Cout,
                                 int M, int N, int K) {
    __shared__ unsigned short As[64][40];
    __shared__ unsigned short Bs[64][40];
    int tid = threadIdx.x;
    int rowBase = blockIdx.y * 64;
    int colBase = blockIdx.x * 64;

    int wave = tid >> 6;
    int l    = tid & 63;
    int wr = wave >> 1, wc = wave & 1;
    int lane16 = l & 15;
    int kb = (l >> 4) * 8;

    int sr = tid >> 2;
    int sk = (tid & 3) << 3;
    const unsigned short* Ap = A + (size_t)(rowBase + sr) * K + sk;
    const unsigned short* Bp = B + (size_t)(colBase + sr) * K + sk;

    f32x4 acc[2][2] = {};

    for (int k0 = 0; k0 < K; k0 += 32) {
        float4 av = *(const float4*)(Ap + k0);
        float4 bv = *(const float4*)(Bp + k0);
        __syncthreads();
        *(float4*)(&As[sr][sk]) = av;
        *(float4*)(&Bs[sr][sk]) = bv;
        __syncthreads();
        bf16x8 a0 = *(const bf16x8*)(&As[wr * 32 + lane16][kb]);
        bf16x8 a1 = *(const bf16x8*)(&As[wr * 32 + 16 + lane16][kb]);
        bf16x8 b0 = *(const bf16x8*)(&Bs[wc * 32 + lane16][kb]);
        bf16x8 b1 = *(const bf16x8*)(&Bs[wc * 32 + 16 + lane16][kb]);
        acc[0][0] = __builtin_amdgcn_mfma_f32_16x16x32_bf16(a0, b0, acc[0][0], 0, 0, 0);
        acc[0][1] = __builtin_amdgcn_mfma_f32_16x16x32_bf16(a0, b1, acc[0][1], 0, 0, 0);
        acc[1][0] = __builtin_amdgcn_mfma_f32_16x16x32_bf16(a1, b0, acc[1][0], 0, 0, 0);
        acc[1][1] = __builtin_amdgcn_mfma_f32_16x16x32_bf16(a1, b1, acc[1][1], 0, 0, 0);
    }

    int crow0 = rowBase + wr * 32 + (l >> 4) * 4;
    int ccol0 = colBase + wc * 32 + lane16;
    float bsv[2];
    #pragma unroll
    for (int j = 0; j < 2; ++j) {
        bsv[j] = bias[ccol0 + j * 16];
        if (BIAS2) bsv[j] += bias2[ccol0 + j * 16];
    }
    #pragma unroll
    for (int i = 0; i < 2; ++i) {
        #pragma unroll
        for (int r = 0; r < 4; ++r) {
            int row = crow0 + i * 16 + r;
            #pragma unroll
            for (int j = 0; j < 2; ++j) {
                float v = acc[i][j][r] + bsv[j];
                if (DO_LRELU) v = lrelu(v);
                size_t off = (size_t)row * N + ccol0 + j * 16;
                if (OUTBF) ((unsigned short*)Cout)[off] = f2bf(v);
                else       ((float*)Cout)[off] = v;
            }
        }
    }
}

// ---------------------------------------------------------------------------
// Split-K bf16 MFMA GEMM: writes f32 partials. (unchanged)
// ---------------------------------------------------------------------------
__global__ void gemm_bf16_splitk_kernel(const unsigned short* __restrict__ A,
                                        const unsigned short* __restrict__ B,
                                        float* __restrict__ part,
                                        int M, int N, int K, int kChunk) {
    __shared__ unsigned short As[64][40];
    __shared__ unsigned short Bs[64][40];
    int tid = threadIdx.x;
    int rowBase = blockIdx.y * 64;
    int colBase = blockIdx.x * 64;
    int s = blockIdx.z;
    int kStart = s * kChunk;
    int kEnd = kStart + kChunk;

    int wave = tid >> 6;
    int l    = tid & 63;
    int wr = wave >> 1, wc = wave & 1;
    int lane16 = l & 15;
    int kb = (l >> 4) * 8;

    int sr = tid >> 2;
    int sk = (tid & 3) << 3;
    const unsigned short* Ap = A + (size_t)(rowBase + sr) * K + sk;
    const unsigned short* Bp = B + (size_t)(colBase + sr) * K + sk;

    f32x4 acc[2][2] = {};

    for (int k0 = kStart; k0 < kEnd; k0 += 32) {
        float4 av = *(const float4*)(Ap + k0);
        float4 bv = *(const float4*)(Bp + k0);
        __syncthreads();
        *(float4*)(&As[sr][sk]) = av;
        *(float4*)(&Bs[sr][sk]) = bv;
        __syncthreads();
        bf16x8 a0 = *(const bf16x8*)(&As[wr * 32 + lane16][kb]);
        bf16x8 a1 = *(const bf16x8*)(&As[wr * 32 + 16 + lane16][kb]);
        bf16x8 b0 = *(const bf16x8*)(&Bs[wc * 32 + lane16][kb]);
        bf16x8 b1 = *(const bf16x8*)(&Bs[wc * 32 + 16 + lane16][kb]);
        acc[0][0] = __builtin_amdgcn_mfma_f32_16x16x32_bf16(a0, b0, acc[0][0], 0, 0, 0);
        acc[0][1] = __builtin_amdgcn_mfma_f32_16x16x32_bf16(a0, b1, acc[0][1], 0, 0, 0);
        acc[1][0] = __builtin_amdgcn_mfma_f32_16x16x32_bf16(a1, b0, acc[1][0], 0, 0, 0);
        acc[1][1] = __builtin_amdgcn_mfma_f32_16x16x32_bf16(a1, b1, acc[1][1], 0, 0, 0);
    }

    float* Cp = part + (size_t)s * M * N;
    int crow0 = rowBase + wr * 32 + (l >> 4) * 4;
    int ccol0 = colBase + wc * 32 + lane16;
    #pragma unroll
    for (int i = 0; i < 2; ++i)
        #pragma unroll
        for (int r = 0; r < 4; ++r) {
            int row = crow0 + i * 16 + r;
            #pragma unroll
            for (int j = 0; j < 2; ++j)
                Cp[(size_t)row * N + ccol0 + j * 16] = acc[i][j][r];
        }
}

// ---------------------------------------------------------------------------
// Split-K reduce. (unchanged, S now 9)
// ---------------------------------------------------------------------------
template<int S>
__global__ void splitk_reduce_kernel(const float* __restrict__ part,
                                     const float* __restrict__ bias,
                                     unsigned short* __restrict__ out,
                                     int MN, int N) {
    int i4 = blockIdx.x * blockDim.x + threadIdx.x;
    if (i4 * 4 >= MN) return;
    float4 acc = ((const float4*)part)[i4];
    #pragma unroll
    for (int s = 1; s < S; ++s) {
        float4 p = ((const float4*)(part + (size_t)s * MN))[i4];
        acc.x += p.x; acc.y += p.y; acc.z += p.z; acc.w += p.w;
    }
    int col4 = i4 % (N / 4);
    float4 bv = ((const float4*)bias)[col4];
    float o0 = lrelu(acc.x + bv.x);
    float o1 = lrelu(acc.y + bv.y);
    float o2 = lrelu(acc.z + bv.z);
    float o3 = lrelu(acc.w + bv.w);
    uint2 p;
    p.x = (unsigned)f2bf(o0) | ((unsigned)f2bf(o1) << 16);
    p.y = (unsigned)f2bf(o2) | ((unsigned)f2bf(o3) << 16);
    ((uint2*)out)[i4] = p;
}

// ---------------------------------------------------------------------------
// LSTM init: HA (bf16) = h0; zero barrier counter.
// ---------------------------------------------------------------------------
__global__ void lstm_init_kernel(const float* __restrict__ h0,
                                 unsigned short* __restrict__ HA,
                                 int* __restrict__ bar) {
    int i = blockIdx.x * blockDim.x + threadIdx.x;
    if (i < 16384) HA[i] = f2bf(h0[i]);
    if (i < 2) bar[i] = 0;
}

// ---------------------------------------------------------------------------
// Persistent LSTM scan. Same compute structure as R6 (W in VGPRs, gx
// register prefetch, H via LDS). Barrier rewritten:
//   arrive : one fetch_add ACQ_REL (single wb+inv)
//   spin   : RELAXED atomic loads (sc1, L2-bypass -> coherent, NO inv/poll)
//   exit   : one agent ACQUIRE fence (single inv) before H reads
// Counter is monotone across the whole scan (re-zeroed by lstm_init each
// call -> graph-replay safe).
// ---------------------------------------------------------------------------
__global__ __launch_bounds__(256) void lstm_scan_kernel(
        const unsigned short* __restrict__ whh_b,   // [4*512][512] bf16
        const unsigned short* __restrict__ HA,      // [32][512] bf16
        const float* __restrict__ c0,               // [32][512] f32
        const float* __restrict__ gx,               // [2048][2048] f32
        const float* __restrict__ done,             // [2048] f32
        unsigned short* __restrict__ feat,          // [2048][512] bf16
        float* __restrict__ hN, float* __restrict__ cN,
        int* __restrict__ bar) {
    __shared__ float mds[2048];
    __shared__ float Gs[4][16][17];
    __shared__ unsigned short Hs[16][520];

    int tid = threadIdx.x;
    int jt = blockIdx.x >> 1;
    int bt = blockIdx.x & 1;

    for (int i = tid; i < 2048; i += 256) mds[i] = 1.0f - done[i];

    // MFMA identity (wave g computes gate g); W fragment -> registers (once)
    int g = tid >> 6;
    int l = tid & 63;
    int lane16 = l & 15;
    int khi = l >> 4;
    const unsigned short* Wp =
        whh_b + ((size_t)g * 512 + jt * 16 + lane16) * 512 + khi * 8;
    bf16x8 wreg[16];
    #pragma unroll
    for (int kk = 0; kk < 16; ++kk)
        wreg[kk] = *(const bf16x8*)(Wp + kk * 32);

    // pointwise identity (thread owns (j,b))
    int jloc = tid & 15;
    int bloc = tid >> 4;
    int j = jt * 16 + jloc;
    int b = bt * 16 + bloc;
    float c_reg = c0[b * 512 + j];

    // prefetch gx for t=0
    const float* gp0 = gx + (size_t)b * 2048 + j;
    float gi = gp0[0], gf = gp0[512], gg = gp0[1024], go = gp0[1536];

    __syncthreads();

    for (int t = 0; t < 64; ++t) {
        // --- cooperative load of our 16-batch half of h_{t-1} into LDS ---
        const unsigned short* Hsrc =
            (t == 0 ? HA : feat + (size_t)(t - 1) * 16384) + bt * 8192;
        const float4* src4 = (const float4*)Hsrc;    // 1024 x float4 (16 KB)
        #pragma unroll
        for (int u0 = 0; u0 < 4; ++u0) {
            int u = tid + u0 * 256;
            float4 v = src4[u];
            int brow = u >> 6;
            int koff = (u & 63) * 8;
            *(float4*)&Hs[brow][koff] = v;
        }
        __syncthreads();

        // --- gate GEMM: W from regs, H from LDS; 2-way split accumulator ---
        f32x4 acc0 = {}, acc1 = {};
        #pragma unroll
        for (int kk = 0; kk < 16; kk += 2) {
            bf16x8 hb0 = *(const bf16x8*)(&Hs[lane16][khi * 8 + kk * 32]);
            bf16x8 hb1 = *(const bf16x8*)(&Hs[lane16][khi * 8 + kk * 32 + 32]);
            acc0 = __builtin_amdgcn_mfma_f32_16x16x32_bf16(wreg[kk],     hb0, acc0, 0, 0, 0);
            acc1 = __builtin_amdgcn_mfma_f32_16x16x32_bf16(wreg[kk + 1], hb1, acc1, 0, 0, 0);
        }
        f32x4 acc = acc0 + acc1;
        #pragma unroll
        for (int r = 0; r < 4; ++r) Gs[g][khi * 4 + r][lane16] = acc[r];

        // --- prefetch next step's gx into regs (read-only; pre-barrier ok) ---
        float gi_n = 0.f, gf_n = 0.f, gg_n = 0.f, go_n = 0.f;
        if (t < 63) {
            const float* gp = gx + (size_t)((t + 1) * 32 + b) * 2048 + j;
            gi_n = gp[0]; gf_n = gp[512]; gg_n = gp[1024]; go_n = gp[1536];
        }
        __syncthreads();

        // --- pointwise update ---
        int row = t * 32 + b;
        float m = mds[row];
        float ai = gi + m * Gs[0][jloc][bloc];
        float af = gf + m * Gs[1][jloc][bloc];
        float ag = gg + m * Gs[2][jloc][bloc];
        float ao = go + m * Gs[3][jloc][bloc];
        float cp = c_reg * m;
        float si = 1.f / (1.f + __expf(-ai));
        float sf = 1.f / (1.f + __expf(-af));
        float so = 1.f / (1.f + __expf(-ao));
        c_reg = sf * cp + si * tanhf(ag);
        float hn = so * tanhf(c_reg);
        feat[(size_t)row * 512 + j] = f2bf(hn);
        if (t == 63) {
            hN[b * 512 + j] = hn;
            cN[b * 512 + j] = c_reg;
        }
        gi = gi_n; gf = gf_n; gg = gg_n; go = go_n;

        // --- grid barrier: release-add, relaxed spin, one acquire fence ---
        if (t < 63) {
            __syncthreads();
            if (tid == 0) {
                int target = (t + 1) * 64;
                __hip_atomic_fetch_add(bar, 1, __ATOMIC_ACQ_REL,
                                       __HIP_MEMORY_SCOPE_AGENT);
                while (__hip_atomic_load(bar, __ATOMIC_RELAXED,
                                         __HIP_MEMORY_SCOPE_AGENT) < target)
                    __builtin_amdgcn_s_sleep(8);
                __builtin_amdgcn_fence(__ATOMIC_ACQUIRE, "agent");
            }
            __syncthreads();
        }
    }
}

// ---------------------------------------------------------------------------
extern "C" void kernel_launch(void* const* d_in, const int* in_sizes, int n_in,
                              void* d_out, int out_size, void* d_ws, size_t ws_size,
                              hipStream_t stream) {
    const float* x    = (const float*)d_in[0];
    const float* done = (const float*)d_in[1];
    const float* h0   = (const float*)d_in[2];
    const float* c0   = (const float*)d_in[3];
    const float* c1w  = (const float*)d_in[4];
    const float* c1b  = (const float*)d_in[5];
    const float* c2w  = (const float*)d_in[6];
    const float* c2b  = (const float*)d_in[7];
    const float* c3w  = (const float*)d_in[8];
    const float* c3b  = (const float*)d_in[9];
    const float* fc1w = (const float*)d_in[10];
    const float* fc1b = (const float*)d_in[11];
    const float* fc2w = (const float*)d_in[12];
    const float* fc2b = (const float*)d_in[13];
    const float* wih  = (const float*)d_in[14];
    const float* whh  = (const float*)d_in[15];
    const float* bih  = (const float*)d_in[16];
    const float* bhh  = (const float*)d_in[17];
    const float* dfw  = (const float*)d_in[18];
    const float* dfb  = (const float*)d_in[19];
    const float* dw   = (const float*)d_in[20];
    const float* db   = (const float*)d_in[21];
    float* out = (float*)d_out;

    const size_t CONV_ELEMS = 57802752;            // 2048*4*84*84
    char* S = (char*)d_ws;
    unsigned short* c1out  = (unsigned short*)S;   S += CONV_ELEMS * 2;
    unsigned short* c2out  = (unsigned short*)S;   S += CONV_ELEMS * 2;
    unsigned short* c3out  = (unsigned short*)S;   S += CONV_ELEMS * 2;
    unsigned short* fc1w_b = (unsigned short*)S;   S += 28901376;
    unsigned short* fc2w_b = (unsigned short*)S;   S += 524288;
    unsigned short* wih_b  = (unsigned short*)S;   S += 2097152;
    unsigned short* whh_b  = (unsigned short*)S;   S += 2097152;
    unsigned short* dfw_b  = (unsigned short*)S;   S += 131072;
    unsigned short* dw_b   = (unsigned short*)S;   S += 16384;
    unsigned short* hfc1_b = (unsigned short*)S;   S += 2097152;
    unsigned short* hfc2_b = (unsigned short*)S;   S += 2097152;
    float*          gx     = (float*)S;            S += 16777216;
    unsigned short* feat_b = (unsigned short*)S;   S += 2097152;
    unsigned short* dfeat_b= (unsigned short*)S;   S += 524288;
    unsigned short* HA     = (unsigned short*)S;   S += 32768;
    float*          part   = (float*)S;            S += 37748736;  // 9x[2048][512] f32
    int*            bar    = (int*)S;              S += 256;

    // --- conv stack ---
    dim3 cgrid(2048, 7);
    conv_tile_kernel<5, false, true><<<cgrid, 256, 0, stream>>>(x,     c1w, c1b, c1out);
    conv_tile_kernel<3, true,  true><<<cgrid, 256, 0, stream>>>(c1out, c2w, c2b, c2out);
    conv_tile_kernel<3, true,  true><<<cgrid, 256, 0, stream>>>(c2out, c3w, c3b, c3out);

    // --- weight conversions ---
    auto cvt = [&](const float* s, unsigned short* d, int n) {
        int n4 = n / 4;
        cvt_bf16_kernel<<<(n4 + 255) / 256, 256, 0, stream>>>(s, d, n4);
    };
    cvt(fc1w, fc1w_b, 14450688);
    cvt(fc2w, fc2w_b, 262144);
    cvt(wih,  wih_b,  1048576);
    cvt(whh,  whh_b,  1048576);
    cvt(dfw,  dfw_b,  65536);
    cvt(dw,   dw_b,   8192);

    // --- fc1: split-K x9 (K = 28224 = 9*3136), then reduce+bias+lrelu ---
    gemm_bf16_splitk_kernel<<<dim3(8, 32, 9), 256, 0, stream>>>(
        c3out, fc1w_b, part, 2048, 512, 28224, 3136);
    splitk_reduce_kernel<9><<<dim3(1024), 256, 0, stream>>>(
        part, fc1b, hfc1_b, 1048576, 512);

    // --- fc2 ---
    gemm_bf16_kernel<true, false, true><<<dim3(8, 32), 256, 0, stream>>>(
        hfc1_b, fc2w_b, fc2b, nullptr, hfc2_b, 2048, 512, 512);

    // --- x-part of LSTM gates ---
    gemm_bf16_kernel<false, true, false><<<dim3(32, 32), 256, 0, stream>>>(
        hfc2_b, wih_b, bih, bhh, gx, 2048, 2048, 512);

    // --- LSTM scan (single persistent launch) ---
    lstm_init_kernel<<<dim3(64), 256, 0, stream>>>(h0, HA, bar);
    lstm_scan_kernel<<<dim3(64), 256, 0, stream>>>(
        whh_b, HA, c0, gx, done, feat_b,
        out + 131072, out + 131072 + 16384, bar);

    // --- discriminator head ---
    gemm_bf16_kernel<true, false, true><<<dim3(2, 32), 256, 0, stream>>>(
        feat_b, dfw_b, dfb, nullptr, dfeat_b, 2048, 128, 512);
    gemm_bf16_kernel<false, false, false><<<dim3(1, 32), 256, 0, stream>>>(
        dfeat_b, dw_b, db, nullptr, out, 2048, 64, 128);
}